// Round 1
// baseline (2127.694 us; speedup 1.0000x reference)
//
#include <hip/hip_runtime.h>
#include <hip/hip_bf16.h>
#include <stdint.h>

#define BATCH 2
#define SEQ   1024
#define DIM   3072
#define KDIM  1024
#define NHEAD 32
#define HDQ   96
#define THR_SIM 0.95f

typedef unsigned short u16;
typedef __attribute__((ext_vector_type(8))) short short8;
typedef __attribute__((ext_vector_type(4))) float f32x4;

__device__ __forceinline__ u16 f2bf(float f) {
  union { float f; unsigned u; } v; v.f = f;
  unsigned r = v.u + 0x7FFFu + ((v.u >> 16) & 1u);
  return (u16)(r >> 16);
}

__device__ __forceinline__ f32x4 mfma16(short8 a, short8 b, f32x4 c) {
  return __builtin_amdgcn_mfma_f32_16x16x32_bf16(a, b, c, 0, 0, 0);
}

// ---------------- fp32 -> bf16 convert (vectorized) ----------------
__global__ void k_cvt_bf16(const float* __restrict__ in, u16* __restrict__ out, int n4) {
  int i = blockIdx.x * blockDim.x + threadIdx.x;
  if (i < n4) {
    float4 v = ((const float4*)in)[i];
    ushort4 o;
    o.x = f2bf(v.x); o.y = f2bf(v.y); o.z = f2bf(v.z); o.w = f2bf(v.w);
    ((ushort4*)out)[i] = o;
  }
}

// ---------------- transpose fp32 (R,C) -> bf16 (C,R) ----------------
__global__ void k_tr_f32_bf16(const float* __restrict__ in, u16* __restrict__ out, int R, int C) {
  __shared__ float t[32][33];
  int c0 = blockIdx.x * 32, r0 = blockIdx.y * 32;
  int tx = threadIdx.x, ty = threadIdx.y; // (32,8)
  #pragma unroll
  for (int k = 0; k < 4; ++k)
    t[ty + 8 * k][tx] = in[(size_t)(r0 + ty + 8 * k) * C + c0 + tx];
  __syncthreads();
  #pragma unroll
  for (int k = 0; k < 4; ++k)
    out[(size_t)(c0 + ty + 8 * k) * R + r0 + tx] = f2bf(t[tx][ty + 8 * k]);
}

// ---------------- transpose bf16 (R,C) -> bf16 (C,R), batched over z ----------------
__global__ void k_tr_bf16(const u16* __restrict__ in, u16* __restrict__ out, int R, int C) {
  __shared__ u16 t[32][33];
  size_t base = (size_t)blockIdx.z * R * C;
  int c0 = blockIdx.x * 32, r0 = blockIdx.y * 32;
  int tx = threadIdx.x, ty = threadIdx.y;
  #pragma unroll
  for (int k = 0; k < 4; ++k)
    t[ty + 8 * k][tx] = in[base + (size_t)(r0 + ty + 8 * k) * C + c0 + tx];
  __syncthreads();
  #pragma unroll
  for (int k = 0; k < 4; ++k)
    out[base + (size_t)(c0 + ty + 8 * k) * R + r0 + tx] = t[tx][ty + 8 * k];
}

// ---------------- GEMM: C(M,N) = A(M,K) @ Bt(N,K)^T (+bias[N]) ----------------
// A,Bt bf16 row-major (K-contiguous). 128x128 tile, BK=32, 4 waves (2x2), reg-staged LDS.
template<bool OUT_BF16, bool BIAS>
__global__ __launch_bounds__(256, 2) void k_gemm_bt(
    const u16* __restrict__ A, const u16* __restrict__ Bt, void* __restrict__ Cv,
    const float* __restrict__ bias, int M, int N, int K,
    long long bsA, long long bsB, long long bsC)
{
  const int zb = blockIdx.y;
  A  += (size_t)zb * bsA;
  Bt += (size_t)zb * bsB;
  u16*   Cb16 = (u16*)Cv + (size_t)zb * bsC;
  float* Cf32 = (float*)Cv + (size_t)zb * bsC;

  __shared__ u16 As[128 * 32];
  __shared__ u16 Bs[128 * 32];
  const int nt = N >> 7;
  const int tm = blockIdx.x / nt, tn = blockIdx.x % nt;
  const int tid = threadIdx.x, lane = tid & 63, wid = tid >> 6;
  const int wr = wid >> 1, wc = wid & 1, li = lane & 15, lg = lane >> 4;

  const int srow = tid >> 2, scol = (tid & 3) * 8;
  const u16* gA0 = A + (size_t)(tm * 128 + srow) * K + scol;
  const u16* gA1 = gA0 + (size_t)64 * K;
  const u16* gB0 = Bt + (size_t)(tn * 128 + srow) * K + scol;
  const u16* gB1 = gB0 + (size_t)64 * K;
  u16* sA0 = As + srow * 32 + scol; u16* sA1 = sA0 + 64 * 32;
  u16* sB0 = Bs + srow * 32 + scol; u16* sB1 = sB0 + 64 * 32;

  f32x4 acc[4][4];
  #pragma unroll
  for (int a = 0; a < 4; ++a)
    #pragma unroll
    for (int b = 0; b < 4; ++b) acc[a][b] = (f32x4){0.f, 0.f, 0.f, 0.f};

  uint4 ra0 = *(const uint4*)gA0, ra1 = *(const uint4*)gA1;
  uint4 rb0 = *(const uint4*)gB0, rb1 = *(const uint4*)gB1;
  const int nk = K >> 5;
  for (int kt = 0; kt < nk; ++kt) {
    __syncthreads();
    *(uint4*)sA0 = ra0; *(uint4*)sA1 = ra1;
    *(uint4*)sB0 = rb0; *(uint4*)sB1 = rb1;
    __syncthreads();
    if (kt + 1 < nk) {
      const int k0 = (kt + 1) << 5;
      ra0 = *(const uint4*)(gA0 + k0); ra1 = *(const uint4*)(gA1 + k0);
      rb0 = *(const uint4*)(gB0 + k0); rb1 = *(const uint4*)(gB1 + k0);
    }
    short8 af[4], bfv[4];
    #pragma unroll
    for (int mf = 0; mf < 4; ++mf)
      af[mf] = *(const short8*)(As + (wr * 64 + mf * 16 + li) * 32 + lg * 8);
    #pragma unroll
    for (int nf = 0; nf < 4; ++nf)
      bfv[nf] = *(const short8*)(Bs + (wc * 64 + nf * 16 + li) * 32 + lg * 8);
    #pragma unroll
    for (int mf = 0; mf < 4; ++mf)
      #pragma unroll
      for (int nf = 0; nf < 4; ++nf)
        acc[mf][nf] = mfma16(af[mf], bfv[nf], acc[mf][nf]);
  }
  // epilogue: C layout col=lane&15, row=(lane>>4)*4+reg
  #pragma unroll
  for (int mf = 0; mf < 4; ++mf) {
    #pragma unroll
    for (int nf = 0; nf < 4; ++nf) {
      const int col = tn * 128 + wc * 64 + nf * 16 + li;
      const float bb = BIAS ? bias[col] : 0.f;
      #pragma unroll
      for (int j = 0; j < 4; ++j) {
        const int row = tm * 128 + wr * 64 + mf * 16 + lg * 4 + j;
        const float v = acc[mf][nf][j] + bb;
        if (OUT_BF16) Cb16[(size_t)row * N + col] = f2bf(v);
        else          Cf32[(size_t)row * N + col] = v;
      }
    }
  }
}

// ---------------- greedy token-replacement scan + in-place gather ----------------
// gram[b] = K K^T (fp32). cond(i,j) = gram[i][j] > 0.95*n_i*n_j, n = max(sqrt(gram_ii),1e-8).
// Fast path: if no (i,j) satisfies cond -> identity, skip sequential scan entirely.
__global__ __launch_bounds__(1024) void k_scan_replace(const float* __restrict__ gram,
                                                       u16* __restrict__ data)
{
  const int b = blockIdx.x;
  const float* g = gram + (size_t)b * SEQ * SEQ;
  u16* dat = data + (size_t)b * SEQ * KDIM;
  __shared__ float nrm[SEQ];
  __shared__ unsigned char used[SEQ];
  __shared__ unsigned char rowAny[SEQ];
  __shared__ short rep[SEQ];
  __shared__ int anyTot;
  const int j = threadIdx.x;
  float nj = sqrtf(fmaxf(g[(size_t)j * SEQ + j], 0.f));
  nj = fmaxf(nj, 1e-8f);
  nrm[j] = nj; used[j] = 0; rep[j] = (short)j;
  if (j == 0) anyTot = 0;
  __syncthreads();
  {
    const float ni = nrm[j];
    int any = 0;
    for (int jj = j + 1; jj < SEQ; ++jj)
      any |= (g[(size_t)j * SEQ + jj] > THR_SIM * ni * nrm[jj]) ? 1 : 0;
    rowAny[j] = (unsigned char)any;
    if (any) atomicAdd(&anyTot, 1);
  }
  __syncthreads();
  if (anyTot != 0) {
    // exact sequential greedy scan (block-uniform branches)
    for (int i = 0; i < SEQ - 1; ++i) {
      if (rowAny[i] && !used[i]) {
        const float t = THR_SIM * nrm[i];
        if (j > i && !used[j] && g[(size_t)i * SEQ + j] > t * nrm[j]) {
          used[j] = 1; rep[j] = (short)i;
        }
        __syncthreads();
      }
    }
    __syncthreads();
    // in-place gather (absorber rows are never themselves replaced)
    const int src = rep[j];
    if (src != j) {
      for (int c = 0; c < KDIM; c += 8)
        *(uint4*)(dat + (size_t)j * KDIM + c) = *(const uint4*)(dat + (size_t)src * KDIM + c);
    }
  }
}

// ---------------- fused attention ----------------
// grid 256 = b(2) x hgroup(4) x qtile(32 rows). 512 threads (8 waves).
// Per head: qn = q_slice @ WqkT^T + bqk -> LDS; scores (32x1024) in regs (waves split keys);
// full-row softmax; P -> LDS bf16; PV (waves split v-dims); fold mean with 1/(32*rowsum).
__global__ __launch_bounds__(512, 2) void k_attn(
    const u16* __restrict__ q_bf, const u16* __restrict__ k_bf,
    const u16* __restrict__ vT, const u16* __restrict__ WqkT,
    const float* __restrict__ bqk, float* __restrict__ meanOut)
{
  const int bid = blockIdx.x;
  const int b = bid & 1, hg = (bid >> 1) & 3, qt = bid >> 3;
  const int q0 = qt * 32;
  const int tid = threadIdx.x, lane = tid & 63, w = tid >> 6;
  const int li = lane & 15, lg = lane >> 4;

  __shared__ u16 qs[32 * HDQ];       // staged q slice (32 x 96)
  __shared__ u16 qn[32 * 1024];      // q_new tile, rows 2048B, XOR-swizzled
  __shared__ u16 Pl[32 * 1024];      // P tile, same layout
  __shared__ float red[8 * 32];
  __shared__ float gmax[32];
  __shared__ float ginv[32];

  const u16* Kb = k_bf + (size_t)b * SEQ * KDIM;
  const u16* Vb = vT + (size_t)b * KDIM * SEQ;

  f32x4 accm[2][8];
  #pragma unroll
  for (int mf = 0; mf < 2; ++mf)
    #pragma unroll
    for (int nf = 0; nf < 8; ++nf) accm[mf][nf] = (f32x4){0.f, 0.f, 0.f, 0.f};

  for (int hh = 0; hh < 8; ++hh) {
    const int h = hg * 8 + hh;
    __syncthreads();
    if (tid < 384) {
      const int row = tid / 12, cc = (tid % 12) * 8;
      *(uint4*)(qs + row * HDQ + cc) =
          *(const uint4*)(q_bf + ((size_t)(b * SEQ + q0 + row)) * DIM + h * HDQ + cc);
    }
    __syncthreads();

    // ---- q_new: wave w computes dims [w*128, w*128+128), K=96 ----
    {
      f32x4 qacc[2][8];
      #pragma unroll
      for (int mf = 0; mf < 2; ++mf)
        #pragma unroll
        for (int nf = 0; nf < 8; ++nf) qacc[mf][nf] = (f32x4){0.f, 0.f, 0.f, 0.f};
      #pragma unroll
      for (int ks = 0; ks < 3; ++ks) {
        short8 a0 = *(const short8*)(qs + li * HDQ + ks * 32 + lg * 8);
        short8 a1 = *(const short8*)(qs + (16 + li) * HDQ + ks * 32 + lg * 8);
        #pragma unroll
        for (int nf = 0; nf < 8; ++nf) {
          const int n = w * 128 + nf * 16 + li;
          short8 bb = *(const short8*)(WqkT + (size_t)n * HDQ + ks * 32 + lg * 8);
          qacc[0][nf] = mfma16(a0, bb, qacc[0][nf]);
          qacc[1][nf] = mfma16(a1, bb, qacc[1][nf]);
        }
      }
      #pragma unroll
      for (int nf = 0; nf < 8; ++nf) {
        const int col = w * 128 + nf * 16 + li;
        const float bb = bqk[col];
        #pragma unroll
        for (int mf = 0; mf < 2; ++mf)
          #pragma unroll
          for (int jj = 0; jj < 4; ++jj) {
            const int row = mf * 16 + lg * 4 + jj;
            unsigned byt = (unsigned)(row * 2048 + col * 2);
            byt ^= (unsigned)((row & 7) << 4);
            *(u16*)((char*)qn + byt) = f2bf(qacc[mf][nf][jj] + bb);
          }
      }
    }
    __syncthreads();

    // ---- scores: wave w covers keys [w*128, w*128+128) ----
    f32x4 acc2[2][8];
    #pragma unroll
    for (int mf = 0; mf < 2; ++mf)
      #pragma unroll
      for (int nf = 0; nf < 8; ++nf) acc2[mf][nf] = (f32x4){0.f, 0.f, 0.f, 0.f};
    {
      const u16* kwb = Kb + (size_t)(w * 128 + li) * KDIM;
      const int row1 = 16 + li;
      #pragma unroll 2
      for (int ks = 0; ks < 32; ++ks) {
        unsigned byt0 = (unsigned)(li * 2048 + ks * 64 + lg * 16) ^ (unsigned)((li & 7) << 4);
        unsigned byt1 = (unsigned)(row1 * 2048 + ks * 64 + lg * 16) ^ (unsigned)((row1 & 7) << 4);
        short8 a0 = *(const short8*)((const char*)qn + byt0);
        short8 a1 = *(const short8*)((const char*)qn + byt1);
        #pragma unroll
        for (int nf = 0; nf < 8; ++nf) {
          short8 bb = *(const short8*)(kwb + (size_t)nf * 16 * KDIM + ks * 32 + lg * 8);
          acc2[0][nf] = mfma16(a0, bb, acc2[0][nf]);
          acc2[1][nf] = mfma16(a1, bb, acc2[1][nf]);
        }
      }
    }
    // scale 1/sqrt(1024)
    #pragma unroll
    for (int mf = 0; mf < 2; ++mf)
      #pragma unroll
      for (int nf = 0; nf < 8; ++nf) acc2[mf][nf] *= 0.03125f;

    // ---- softmax over all 1024 keys (full rows across 8 waves) ----
    float rmax[2][4];
    #pragma unroll
    for (int mf = 0; mf < 2; ++mf)
      #pragma unroll
      for (int jj = 0; jj < 4; ++jj) {
        float m = -1e30f;
        #pragma unroll
        for (int nf = 0; nf < 8; ++nf) m = fmaxf(m, acc2[mf][nf][jj]);
        rmax[mf][jj] = m;
      }
    #pragma unroll
    for (int d2 = 1; d2 < 16; d2 <<= 1)
      #pragma unroll
      for (int mf = 0; mf < 2; ++mf)
        #pragma unroll
        for (int jj = 0; jj < 4; ++jj)
          rmax[mf][jj] = fmaxf(rmax[mf][jj], __shfl_xor(rmax[mf][jj], d2));
    if (li == 0) {
      #pragma unroll
      for (int mf = 0; mf < 2; ++mf)
        #pragma unroll
        for (int jj = 0; jj < 4; ++jj)
          red[w * 32 + mf * 16 + lg * 4 + jj] = rmax[mf][jj];
    }
    __syncthreads();
    if (tid < 32) {
      float m = red[tid];
      #pragma unroll
      for (int ww = 1; ww < 8; ++ww) m = fmaxf(m, red[ww * 32 + tid]);
      gmax[tid] = m;
    }
    __syncthreads();
    float gm[2][4];
    #pragma unroll
    for (int mf = 0; mf < 2; ++mf)
      #pragma unroll
      for (int jj = 0; jj < 4; ++jj) gm[mf][jj] = gmax[mf * 16 + lg * 4 + jj];
    float rsum[2][4] = {{0.f,0.f,0.f,0.f},{0.f,0.f,0.f,0.f}};
    #pragma unroll
    for (int mf = 0; mf < 2; ++mf)
      #pragma unroll
      for (int nf = 0; nf < 8; ++nf)
        #pragma unroll
        for (int jj = 0; jj < 4; ++jj) {
          float pv = __expf(acc2[mf][nf][jj] - gm[mf][jj]);
          acc2[mf][nf][jj] = pv;
          rsum[mf][jj] += pv;
        }
    #pragma unroll
    for (int d2 = 1; d2 < 16; d2 <<= 1)
      #pragma unroll
      for (int mf = 0; mf < 2; ++mf)
        #pragma unroll
        for (int jj = 0; jj < 4; ++jj)
          rsum[mf][jj] += __shfl_xor(rsum[mf][jj], d2);
    if (li == 0) {
      #pragma unroll
      for (int mf = 0; mf < 2; ++mf)
        #pragma unroll
        for (int jj = 0; jj < 4; ++jj)
          red[w * 32 + mf * 16 + lg * 4 + jj] = rsum[mf][jj];
    }
    __syncthreads();
    if (tid < 32) {
      float s2 = 0.f;
      #pragma unroll
      for (int ww = 0; ww < 8; ++ww) s2 += red[ww * 32 + tid];
      ginv[tid] = 1.f / (32.f * s2);
    }
    // write P (bf16, swizzled)
    #pragma unroll
    for (int nf = 0; nf < 8; ++nf) {
      const int col = w * 128 + nf * 16 + li;
      #pragma unroll
      for (int mf = 0; mf < 2; ++mf)
        #pragma unroll
        for (int jj = 0; jj < 4; ++jj) {
          const int row = mf * 16 + lg * 4 + jj;
          unsigned byt = (unsigned)(row * 2048 + col * 2) ^ (unsigned)((row & 7) << 4);
          *(u16*)((char*)Pl + byt) = f2bf(acc2[mf][nf][jj]);
        }
    }
    __syncthreads();

    // ---- PV: wave w covers v-dims [w*128, w*128+128) ----
    #pragma unroll
    for (int mf = 0; mf < 2; ++mf)
      #pragma unroll
      for (int nf = 0; nf < 8; ++nf) acc2[mf][nf] = (f32x4){0.f, 0.f, 0.f, 0.f};
    {
      const u16* vwb = Vb + (size_t)(w * 128 + li) * SEQ;
      const int row1 = 16 + li;
      #pragma unroll 2
      for (int ks = 0; ks < 32; ++ks) {
        unsigned byt0 = (unsigned)(li * 2048 + ks * 64 + lg * 16) ^ (unsigned)((li & 7) << 4);
        unsigned byt1 = (unsigned)(row1 * 2048 + ks * 64 + lg * 16) ^ (unsigned)((row1 & 7) << 4);
        short8 a0 = *(const short8*)((const char*)Pl + byt0);
        short8 a1 = *(const short8*)((const char*)Pl + byt1);
        #pragma unroll
        for (int nf = 0; nf < 8; ++nf) {
          short8 vv = *(const short8*)(vwb + (size_t)nf * 16 * SEQ + ks * 32 + lg * 8);
          acc2[0][nf] = mfma16(a0, vv, acc2[0][nf]);
          acc2[1][nf] = mfma16(a1, vv, acc2[1][nf]);
        }
      }
    }
    float gi[2][4];
    #pragma unroll
    for (int mf = 0; mf < 2; ++mf)
      #pragma unroll
      for (int jj = 0; jj < 4; ++jj) gi[mf][jj] = ginv[mf * 16 + lg * 4 + jj];
    #pragma unroll
    for (int mf = 0; mf < 2; ++mf)
      #pragma unroll
      for (int nf = 0; nf < 8; ++nf)
        #pragma unroll
        for (int jj = 0; jj < 4; ++jj)
          accm[mf][nf][jj] += acc2[mf][nf][jj] * gi[mf][jj];
  } // heads

  // mean over heads: 4 head-groups -> 4 atomics per element
  #pragma unroll
  for (int mf = 0; mf < 2; ++mf)
    #pragma unroll
    for (int nf = 0; nf < 8; ++nf)
      #pragma unroll
      for (int jj = 0; jj < 4; ++jj) {
        const int row = q0 + mf * 16 + lg * 4 + jj;
        const int col = w * 128 + nf * 16 + li;
        __hip_atomic_fetch_add(meanOut + ((size_t)b * SEQ + row) * KDIM + col,
                               accm[mf][nf][jj], __ATOMIC_RELAXED, __HIP_MEMORY_SCOPE_AGENT);
      }
}

// ---------------- host ----------------
extern "C" void kernel_launch(void* const* d_in, const int* in_sizes, int n_in,
                              void* d_out, int out_size, void* d_ws, size_t ws_size,
                              hipStream_t stream)
{
  (void)in_sizes; (void)n_in; (void)out_size;
  const float* hs  = (const float*)d_in[0];
  const float* Wq  = (const float*)d_in[1];
  const float* bq  = (const float*)d_in[2];
  const float* Wk  = (const float*)d_in[3];
  const float* bk  = (const float*)d_in[4];
  const float* Wv  = (const float*)d_in[5];
  const float* bv  = (const float*)d_in[6];
  const float* Wqk = (const float*)d_in[7];
  const float* bqk = (const float*)d_in[8];
  const float* Wo  = (const float*)d_in[9];
  const float* bo  = (const float*)d_in[10];

  // workspace layout (region reuse; lifetimes are sequential on the stream):
  char* p = (char*)d_ws;
  u16*   hs_bf   = (u16*)(p + 0);                    // 12.58 MB, dead after gemm v
  u16*   vTb     = (u16*)(p + 0);                    // 4.19 MB (after hs_bf dead)
  u16*   mean_bf = (u16*)(p + 4194304);              // 4.19 MB
  u16*   WqT     = (u16*)(p + 12582912);             // 18.87 MB, dead after gemm q
  float* gram    = (float*)(p + 12582912);           // 8.39 MB  (after WqT dead)
  u16*   WoT     = (u16*)(p + 12582912);             // 6.29 MB  (after gram dead)
  float* meanf   = (float*)(p + 12582912 + 8388608); // 8.39 MB
  u16*   WkT     = (u16*)(p + 31457280);             // 6.29 MB
  u16*   WvT     = WkT;                              // (after WkT dead)
  u16*   WqkT    = (u16*)(p + 37748736);             // 0.20 MB
  u16*   q_bf    = (u16*)(p + 37945344);             // 12.58 MB
  u16*   k_bf    = (u16*)(p + 50528256);             // 4.19 MB
  u16*   v_bf    = (u16*)(p + 54722560);             // 4.19 MB
  if (ws_size < 58916864) return;

  const dim3 tb(32, 8);

  k_cvt_bf16<<<6144, 256, 0, stream>>>(hs, hs_bf, BATCH * SEQ * DIM / 4);
  k_tr_f32_bf16<<<dim3(96, 96), tb, 0, stream>>>(Wq, WqT, DIM, DIM);
  k_gemm_bt<true, true><<<dim3(16 * 24, 1), 256, 0, stream>>>(hs_bf, WqT, q_bf, bq, 2048, DIM, DIM, 0, 0, 0);
  k_tr_f32_bf16<<<dim3(32, 96), tb, 0, stream>>>(Wk, WkT, DIM, KDIM);
  k_gemm_bt<true, true><<<dim3(16 * 8, 1), 256, 0, stream>>>(hs_bf, WkT, k_bf, bk, 2048, KDIM, DIM, 0, 0, 0);
  k_gemm_bt<false, false><<<dim3(8 * 8, 2), 256, 0, stream>>>(k_bf, k_bf, gram, nullptr, SEQ, SEQ, KDIM,
                                                              (long long)SEQ * KDIM, (long long)SEQ * KDIM,
                                                              (long long)SEQ * SEQ);
  k_scan_replace<<<2, 1024, 0, stream>>>(gram, k_bf);
  k_tr_f32_bf16<<<dim3(32, 96), tb, 0, stream>>>(Wv, WvT, DIM, KDIM);
  k_gemm_bt<true, true><<<dim3(16 * 8, 1), 256, 0, stream>>>(hs_bf, WvT, v_bf, bv, 2048, KDIM, DIM, 0, 0, 0);
  k_gemm_bt<false, false><<<dim3(8 * 8, 2), 256, 0, stream>>>(v_bf, v_bf, gram, nullptr, SEQ, SEQ, KDIM,
                                                              (long long)SEQ * KDIM, (long long)SEQ * KDIM,
                                                              (long long)SEQ * SEQ);
  k_scan_replace<<<2, 1024, 0, stream>>>(gram, v_bf);
  k_tr_f32_bf16<<<dim3(96, 32), tb, 0, stream>>>(Wo, WoT, KDIM, DIM);
  k_tr_bf16<<<dim3(32, 32, 2), tb, 0, stream>>>(v_bf, vTb, SEQ, KDIM);
  k_tr_f32_bf16<<<dim3(32, 3), tb, 0, stream>>>(Wqk, WqkT, HDQ, KDIM);
  hipMemsetAsync(meanf, 0, (size_t)BATCH * SEQ * KDIM * sizeof(float), stream);
  k_attn<<<256, 512, 0, stream>>>(q_bf, k_bf, vTb, WqkT, bqk, meanf);
  k_cvt_bf16<<<2048, 256, 0, stream>>>(meanf, mean_bf, BATCH * SEQ * KDIM / 4);
  k_gemm_bt<false, true><<<dim3(16 * 24, 1), 256, 0, stream>>>(mean_bf, WoT, (float*)d_out, bo, 2048, DIM, KDIM, 0, 0, 0);
}

// Round 2
// 1567.856 us; speedup vs baseline: 1.3571x; 1.3571x over previous
//
#include <hip/hip_runtime.h>
#include <hip/hip_bf16.h>
#include <stdint.h>

#define BATCH 2
#define SEQ   1024
#define DIM   3072
#define KDIM  1024
#define NHEAD 32
#define HDQ   96
#define THR_SIM 0.95f

typedef unsigned short u16;
typedef __attribute__((ext_vector_type(8))) short short8;
typedef __attribute__((ext_vector_type(4))) float f32x4;

__device__ __forceinline__ u16 f2bf(float f) {
  union { float f; unsigned u; } v; v.f = f;
  unsigned r = v.u + 0x7FFFu + ((v.u >> 16) & 1u);
  return (u16)(r >> 16);
}

__device__ __forceinline__ f32x4 mfma16(short8 a, short8 b, f32x4 c) {
  return __builtin_amdgcn_mfma_f32_16x16x32_bf16(a, b, c, 0, 0, 0);
}

// ---------------- fp32 -> bf16 convert (vectorized) ----------------
__global__ void k_cvt_bf16(const float* __restrict__ in, u16* __restrict__ out, int n4) {
  int i = blockIdx.x * blockDim.x + threadIdx.x;
  if (i < n4) {
    float4 v = ((const float4*)in)[i];
    ushort4 o;
    o.x = f2bf(v.x); o.y = f2bf(v.y); o.z = f2bf(v.z); o.w = f2bf(v.w);
    ((ushort4*)out)[i] = o;
  }
}

// ---------------- transpose fp32 (R,C) -> bf16 (C,R) ----------------
__global__ void k_tr_f32_bf16(const float* __restrict__ in, u16* __restrict__ out, int R, int C) {
  __shared__ float t[32][33];
  int c0 = blockIdx.x * 32, r0 = blockIdx.y * 32;
  int tx = threadIdx.x, ty = threadIdx.y; // (32,8)
  #pragma unroll
  for (int k = 0; k < 4; ++k)
    t[ty + 8 * k][tx] = in[(size_t)(r0 + ty + 8 * k) * C + c0 + tx];
  __syncthreads();
  #pragma unroll
  for (int k = 0; k < 4; ++k)
    out[(size_t)(c0 + ty + 8 * k) * R + r0 + tx] = f2bf(t[tx][ty + 8 * k]);
}

// ---------------- transpose bf16 (R,C) -> bf16 (C,R), batched over z ----------------
__global__ void k_tr_bf16(const u16* __restrict__ in, u16* __restrict__ out, int R, int C) {
  __shared__ u16 t[32][33];
  size_t base = (size_t)blockIdx.z * R * C;
  int c0 = blockIdx.x * 32, r0 = blockIdx.y * 32;
  int tx = threadIdx.x, ty = threadIdx.y;
  #pragma unroll
  for (int k = 0; k < 4; ++k)
    t[ty + 8 * k][tx] = in[base + (size_t)(r0 + ty + 8 * k) * C + c0 + tx];
  __syncthreads();
  #pragma unroll
  for (int k = 0; k < 4; ++k)
    out[base + (size_t)(c0 + ty + 8 * k) * R + r0 + tx] = t[tx][ty + 8 * k];
}

// ---------------- GEMM: C(M,N) = A(M,K) @ Bt(N,K)^T (+bias[N]) ----------------
template<bool OUT_BF16, bool BIAS>
__global__ __launch_bounds__(256, 2) void k_gemm_bt(
    const u16* __restrict__ A, const u16* __restrict__ Bt, void* __restrict__ Cv,
    const float* __restrict__ bias, int M, int N, int K,
    long long bsA, long long bsB, long long bsC)
{
  const int zb = blockIdx.y;
  A  += (size_t)zb * bsA;
  Bt += (size_t)zb * bsB;
  u16*   Cb16 = (u16*)Cv + (size_t)zb * bsC;
  float* Cf32 = (float*)Cv + (size_t)zb * bsC;

  __shared__ u16 As[128 * 32];
  __shared__ u16 Bs[128 * 32];
  const int nt = N >> 7;
  const int tm = blockIdx.x / nt, tn = blockIdx.x % nt;
  const int tid = threadIdx.x, lane = tid & 63, wid = tid >> 6;
  const int wr = wid >> 1, wc = wid & 1, li = lane & 15, lg = lane >> 4;

  const int srow = tid >> 2, scol = (tid & 3) * 8;
  const u16* gA0 = A + (size_t)(tm * 128 + srow) * K + scol;
  const u16* gA1 = gA0 + (size_t)64 * K;
  const u16* gB0 = Bt + (size_t)(tn * 128 + srow) * K + scol;
  const u16* gB1 = gB0 + (size_t)64 * K;
  u16* sA0 = As + srow * 32 + scol; u16* sA1 = sA0 + 64 * 32;
  u16* sB0 = Bs + srow * 32 + scol; u16* sB1 = sB0 + 64 * 32;

  f32x4 acc[4][4];
  #pragma unroll
  for (int a = 0; a < 4; ++a)
    #pragma unroll
    for (int b = 0; b < 4; ++b) acc[a][b] = (f32x4){0.f, 0.f, 0.f, 0.f};

  uint4 ra0 = *(const uint4*)gA0, ra1 = *(const uint4*)gA1;
  uint4 rb0 = *(const uint4*)gB0, rb1 = *(const uint4*)gB1;
  const int nk = K >> 5;
  for (int kt = 0; kt < nk; ++kt) {
    __syncthreads();
    *(uint4*)sA0 = ra0; *(uint4*)sA1 = ra1;
    *(uint4*)sB0 = rb0; *(uint4*)sB1 = rb1;
    __syncthreads();
    if (kt + 1 < nk) {
      const int k0 = (kt + 1) << 5;
      ra0 = *(const uint4*)(gA0 + k0); ra1 = *(const uint4*)(gA1 + k0);
      rb0 = *(const uint4*)(gB0 + k0); rb1 = *(const uint4*)(gB1 + k0);
    }
    short8 af[4], bfv[4];
    #pragma unroll
    for (int mf = 0; mf < 4; ++mf)
      af[mf] = *(const short8*)(As + (wr * 64 + mf * 16 + li) * 32 + lg * 8);
    #pragma unroll
    for (int nf = 0; nf < 4; ++nf)
      bfv[nf] = *(const short8*)(Bs + (wc * 64 + nf * 16 + li) * 32 + lg * 8);
    #pragma unroll
    for (int mf = 0; mf < 4; ++mf)
      #pragma unroll
      for (int nf = 0; nf < 4; ++nf)
        acc[mf][nf] = mfma16(af[mf], bfv[nf], acc[mf][nf]);
  }
  #pragma unroll
  for (int mf = 0; mf < 4; ++mf) {
    #pragma unroll
    for (int nf = 0; nf < 4; ++nf) {
      const int col = tn * 128 + wc * 64 + nf * 16 + li;
      const float bb = BIAS ? bias[col] : 0.f;
      #pragma unroll
      for (int j = 0; j < 4; ++j) {
        const int row = tm * 128 + wr * 64 + mf * 16 + lg * 4 + j;
        const float v = acc[mf][nf][j] + bb;
        if (OUT_BF16) Cb16[(size_t)row * N + col] = f2bf(v);
        else          Cf32[(size_t)row * N + col] = v;
      }
    }
  }
}

// ---------------- token replacement: norms, rowAny (parallel), scan+gather ----------------
__global__ void k_norms(const float* __restrict__ gram, float* __restrict__ nrm,
                        int* __restrict__ anyCnt) {
  const int b = blockIdx.x, j = threadIdx.x;
  const float* g = gram + (size_t)b * SEQ * SEQ;
  float nj = fmaxf(sqrtf(fmaxf(g[(size_t)j * SEQ + j], 0.f)), 1e-8f);
  nrm[b * SEQ + j] = nj;
  if (j == 0) anyCnt[b] = 0;
}

__global__ void k_rowany(const float* __restrict__ gram, const float* __restrict__ nrm,
                         unsigned char* __restrict__ rowAny, int* __restrict__ anyCnt) {
  const int i = blockIdx.x, b = blockIdx.y, t = threadIdx.x; // 256 threads
  const float* g = gram + (size_t)b * SEQ * SEQ + (size_t)i * SEQ;
  const float* nr = nrm + b * SEQ;
  const float ni = nr[i];
  int any = 0;
  for (int j = i + 1 + t; j < SEQ; j += 256)
    any |= (g[j] > THR_SIM * ni * nr[j]) ? 1 : 0;
  any = __any(any) ? 1 : 0;
  __shared__ int s[4];
  if ((t & 63) == 0) s[t >> 6] = any;
  __syncthreads();
  if (t == 0) {
    int a = s[0] | s[1] | s[2] | s[3];
    rowAny[b * SEQ + i] = (unsigned char)a;
    if (a) atomicAdd(&anyCnt[b], 1);
  }
}

__global__ __launch_bounds__(1024) void k_scan_replace(
    const float* __restrict__ gram, const float* __restrict__ nrmG,
    const unsigned char* __restrict__ rowAnyG, const int* __restrict__ anyCnt,
    u16* __restrict__ data)
{
  const int b = blockIdx.x;
  if (anyCnt[b] == 0) return;  // block-uniform fast path
  const float* g = gram + (size_t)b * SEQ * SEQ;
  u16* dat = data + (size_t)b * SEQ * KDIM;
  __shared__ float nrm[SEQ];
  __shared__ unsigned char used[SEQ];
  __shared__ unsigned char rowAny[SEQ];
  __shared__ short rep[SEQ];
  const int j = threadIdx.x;
  nrm[j] = nrmG[b * SEQ + j];
  rowAny[j] = rowAnyG[b * SEQ + j];
  used[j] = 0; rep[j] = (short)j;
  __syncthreads();
  for (int i = 0; i < SEQ - 1; ++i) {
    if (rowAny[i] && !used[i]) {
      const float t = THR_SIM * nrm[i];
      if (j > i && !used[j] && g[(size_t)i * SEQ + j] > t * nrm[j]) {
        used[j] = 1; rep[j] = (short)i;
      }
      __syncthreads();
    }
  }
  __syncthreads();
  const int src = rep[j];
  if (src != j) {
    for (int c = 0; c < KDIM; c += 8)
      *(uint4*)(dat + (size_t)j * KDIM + c) = *(const uint4*)(dat + (size_t)src * KDIM + c);
  }
}

// ---------------- fused attention ----------------
// grid 512 = xcd-clustered (b, hg in [0,8) of 4 heads, qtile of 32 rows). 512 threads (8 waves).
// LDS: one 64KB tile buffer aliased between q_new and P (both XOR-swizzled).
__global__ __launch_bounds__(512, 4) void k_attn(
    const u16* __restrict__ q_bf, const u16* __restrict__ k_bf,
    const u16* __restrict__ vT, const u16* __restrict__ WqkT,
    const float* __restrict__ bqk, float* __restrict__ meanOut)
{
  const int bid = blockIdx.x;
  // XCD-clustered map: xcd = bid&7 -> fixes batch (K/V working set = 4MB = one L2)
  const int xcd = bid & 7, idx = bid >> 3;
  const int b = xcd >> 2;
  const int hg = ((xcd & 3) << 1) | (idx & 1);   // 8 head-groups of 4 heads
  const int qt = idx >> 1;                        // 32 q-tiles of 32 rows
  const int q0 = qt * 32;
  const int tid = threadIdx.x, lane = tid & 63, w = tid >> 6;
  const int li = lane & 15, lg = lane >> 4;

  __shared__ u16 qs[32 * HDQ];       // staged q slice (32 x 96)
  __shared__ u16 sT[32 * 1024];      // q_new tile, then P tile (rows 2048B, XOR-swizzled)
  __shared__ float red[8 * 32];
  __shared__ float gmax[32];
  __shared__ float ginv[32];

  const u16* Kb = k_bf + (size_t)b * SEQ * KDIM;
  const u16* Vb = vT + (size_t)b * KDIM * SEQ;

  f32x4 accm[2][8];
  #pragma unroll
  for (int mf = 0; mf < 2; ++mf)
    #pragma unroll
    for (int nf = 0; nf < 8; ++nf) accm[mf][nf] = (f32x4){0.f, 0.f, 0.f, 0.f};

  for (int hh = 0; hh < 4; ++hh) {
    const int h = hg * 4 + hh;
    __syncthreads();
    if (tid < 384) {
      const int row = tid / 12, cc = (tid % 12) * 8;
      *(uint4*)(qs + row * HDQ + cc) =
          *(const uint4*)(q_bf + ((size_t)(b * SEQ + q0 + row)) * DIM + h * HDQ + cc);
    }
    __syncthreads();

    // ---- q_new: wave w computes dims [w*128, w*128+128), K=96 ----
    {
      f32x4 qacc[2][8];
      #pragma unroll
      for (int mf = 0; mf < 2; ++mf)
        #pragma unroll
        for (int nf = 0; nf < 8; ++nf) qacc[mf][nf] = (f32x4){0.f, 0.f, 0.f, 0.f};
      #pragma unroll
      for (int ks = 0; ks < 3; ++ks) {
        short8 a0 = *(const short8*)(qs + li * HDQ + ks * 32 + lg * 8);
        short8 a1 = *(const short8*)(qs + (16 + li) * HDQ + ks * 32 + lg * 8);
        #pragma unroll
        for (int nf = 0; nf < 8; ++nf) {
          const int n = w * 128 + nf * 16 + li;
          short8 bb = *(const short8*)(WqkT + (size_t)n * HDQ + ks * 32 + lg * 8);
          qacc[0][nf] = mfma16(a0, bb, qacc[0][nf]);
          qacc[1][nf] = mfma16(a1, bb, qacc[1][nf]);
        }
      }
      #pragma unroll
      for (int nf = 0; nf < 8; ++nf) {
        const int col = w * 128 + nf * 16 + li;
        const float bb = bqk[col];
        #pragma unroll
        for (int mf = 0; mf < 2; ++mf)
          #pragma unroll
          for (int jj = 0; jj < 4; ++jj) {
            const int row = mf * 16 + lg * 4 + jj;
            unsigned byt = (unsigned)(row * 2048 + col * 2);
            byt ^= (unsigned)((row & 7) << 4);
            *(u16*)((char*)sT + byt) = f2bf(qacc[mf][nf][jj] + bb);
          }
      }
    }
    __syncthreads();

    // ---- scores: wave w covers keys [w*128, w*128+128) ----
    f32x4 acc2[2][8];
    #pragma unroll
    for (int mf = 0; mf < 2; ++mf)
      #pragma unroll
      for (int nf = 0; nf < 8; ++nf) acc2[mf][nf] = (f32x4){0.f, 0.f, 0.f, 0.f};
    {
      const u16* kwb = Kb + (size_t)(w * 128 + li) * KDIM;
      const int row1 = 16 + li;
      #pragma unroll 2
      for (int ks = 0; ks < 32; ++ks) {
        unsigned byt0 = (unsigned)(li * 2048 + ks * 64 + lg * 16) ^ (unsigned)((li & 7) << 4);
        unsigned byt1 = (unsigned)(row1 * 2048 + ks * 64 + lg * 16) ^ (unsigned)((row1 & 7) << 4);
        short8 a0 = *(const short8*)((const char*)sT + byt0);
        short8 a1 = *(const short8*)((const char*)sT + byt1);
        #pragma unroll
        for (int nf = 0; nf < 8; ++nf) {
          short8 bb = *(const short8*)(kwb + (size_t)nf * 16 * KDIM + ks * 32 + lg * 8);
          acc2[0][nf] = mfma16(a0, bb, acc2[0][nf]);
          acc2[1][nf] = mfma16(a1, bb, acc2[1][nf]);
        }
      }
    }
    #pragma unroll
    for (int mf = 0; mf < 2; ++mf)
      #pragma unroll
      for (int nf = 0; nf < 8; ++nf) acc2[mf][nf] *= 0.03125f;

    // ---- softmax over all 1024 keys ----
    float rmax[2][4];
    #pragma unroll
    for (int mf = 0; mf < 2; ++mf)
      #pragma unroll
      for (int jj = 0; jj < 4; ++jj) {
        float m = -1e30f;
        #pragma unroll
        for (int nf = 0; nf < 8; ++nf) m = fmaxf(m, acc2[mf][nf][jj]);
        rmax[mf][jj] = m;
      }
    #pragma unroll
    for (int d2 = 1; d2 < 16; d2 <<= 1)
      #pragma unroll
      for (int mf = 0; mf < 2; ++mf)
        #pragma unroll
        for (int jj = 0; jj < 4; ++jj)
          rmax[mf][jj] = fmaxf(rmax[mf][jj], __shfl_xor(rmax[mf][jj], d2));
    if (li == 0) {
      #pragma unroll
      for (int mf = 0; mf < 2; ++mf)
        #pragma unroll
        for (int jj = 0; jj < 4; ++jj)
          red[w * 32 + mf * 16 + lg * 4 + jj] = rmax[mf][jj];
    }
    __syncthreads();
    if (tid < 32) {
      float m = red[tid];
      #pragma unroll
      for (int ww = 1; ww < 8; ++ww) m = fmaxf(m, red[ww * 32 + tid]);
      gmax[tid] = m;
    }
    __syncthreads();
    float gm[2][4];
    #pragma unroll
    for (int mf = 0; mf < 2; ++mf)
      #pragma unroll
      for (int jj = 0; jj < 4; ++jj) gm[mf][jj] = gmax[mf * 16 + lg * 4 + jj];
    float rsum[2][4] = {{0.f,0.f,0.f,0.f},{0.f,0.f,0.f,0.f}};
    #pragma unroll
    for (int mf = 0; mf < 2; ++mf)
      #pragma unroll
      for (int nf = 0; nf < 8; ++nf)
        #pragma unroll
        for (int jj = 0; jj < 4; ++jj) {
          float pv = __expf(acc2[mf][nf][jj] - gm[mf][jj]);
          acc2[mf][nf][jj] = pv;
          rsum[mf][jj] += pv;
        }
    #pragma unroll
    for (int d2 = 1; d2 < 16; d2 <<= 1)
      #pragma unroll
      for (int mf = 0; mf < 2; ++mf)
        #pragma unroll
        for (int jj = 0; jj < 4; ++jj)
          rsum[mf][jj] += __shfl_xor(rsum[mf][jj], d2);
    if (li == 0) {
      #pragma unroll
      for (int mf = 0; mf < 2; ++mf)
        #pragma unroll
        for (int jj = 0; jj < 4; ++jj)
          red[w * 32 + mf * 16 + lg * 4 + jj] = rsum[mf][jj];
    }
    __syncthreads();   // postdates ALL sT(q_new) reads -> safe to overwrite with P
    if (tid < 32) {
      float s2 = 0.f;
      #pragma unroll
      for (int ww = 0; ww < 8; ++ww) s2 += red[ww * 32 + tid];
      ginv[tid] = 1.f / (32.f * s2);
    }
    // write P (bf16, swizzled) into sT
    #pragma unroll
    for (int nf = 0; nf < 8; ++nf) {
      const int col = w * 128 + nf * 16 + li;
      #pragma unroll
      for (int mf = 0; mf < 2; ++mf)
        #pragma unroll
        for (int jj = 0; jj < 4; ++jj) {
          const int row = mf * 16 + lg * 4 + jj;
          unsigned byt = (unsigned)(row * 2048 + col * 2) ^ (unsigned)((row & 7) << 4);
          *(u16*)((char*)sT + byt) = f2bf(acc2[mf][nf][jj]);
        }
    }
    __syncthreads();

    // ---- PV: wave w covers v-dims [w*128, w*128+128) ----
    #pragma unroll
    for (int mf = 0; mf < 2; ++mf)
      #pragma unroll
      for (int nf = 0; nf < 8; ++nf) acc2[mf][nf] = (f32x4){0.f, 0.f, 0.f, 0.f};
    {
      const u16* vwb = Vb + (size_t)(w * 128 + li) * SEQ;
      const int row1 = 16 + li;
      #pragma unroll 2
      for (int ks = 0; ks < 32; ++ks) {
        unsigned byt0 = (unsigned)(li * 2048 + ks * 64 + lg * 16) ^ (unsigned)((li & 7) << 4);
        unsigned byt1 = (unsigned)(row1 * 2048 + ks * 64 + lg * 16) ^ (unsigned)((row1 & 7) << 4);
        short8 a0 = *(const short8*)((const char*)sT + byt0);
        short8 a1 = *(const short8*)((const char*)sT + byt1);
        #pragma unroll
        for (int nf = 0; nf < 8; ++nf) {
          short8 vv = *(const short8*)(vwb + (size_t)nf * 16 * SEQ + ks * 32 + lg * 8);
          acc2[0][nf] = mfma16(a0, vv, acc2[0][nf]);
          acc2[1][nf] = mfma16(a1, vv, acc2[1][nf]);
        }
      }
    }
    float gi[2][4];
    #pragma unroll
    for (int mf = 0; mf < 2; ++mf)
      #pragma unroll
      for (int jj = 0; jj < 4; ++jj) gi[mf][jj] = ginv[mf * 16 + lg * 4 + jj];
    #pragma unroll
    for (int mf = 0; mf < 2; ++mf)
      #pragma unroll
      for (int nf = 0; nf < 8; ++nf)
        #pragma unroll
        for (int jj = 0; jj < 4; ++jj)
          accm[mf][nf][jj] += acc2[mf][nf][jj] * gi[mf][jj];
  } // heads

  // mean over heads: 8 head-groups -> 8 atomics per element
  #pragma unroll
  for (int mf = 0; mf < 2; ++mf)
    #pragma unroll
    for (int nf = 0; nf < 8; ++nf)
      #pragma unroll
      for (int jj = 0; jj < 4; ++jj) {
        const int row = q0 + mf * 16 + lg * 4 + jj;
        const int col = w * 128 + nf * 16 + li;
        __hip_atomic_fetch_add(meanOut + ((size_t)b * SEQ + row) * KDIM + col,
                               accm[mf][nf][jj], __ATOMIC_RELAXED, __HIP_MEMORY_SCOPE_AGENT);
      }
}

// ---------------- host ----------------
extern "C" void kernel_launch(void* const* d_in, const int* in_sizes, int n_in,
                              void* d_out, int out_size, void* d_ws, size_t ws_size,
                              hipStream_t stream)
{
  (void)in_sizes; (void)n_in; (void)out_size;
  const float* hs  = (const float*)d_in[0];
  const float* Wq  = (const float*)d_in[1];
  const float* bq  = (const float*)d_in[2];
  const float* Wk  = (const float*)d_in[3];
  const float* bk  = (const float*)d_in[4];
  const float* Wv  = (const float*)d_in[5];
  const float* bv  = (const float*)d_in[6];
  const float* Wqk = (const float*)d_in[7];
  const float* bqk = (const float*)d_in[8];
  const float* Wo  = (const float*)d_in[9];
  const float* bo  = (const float*)d_in[10];

  char* p = (char*)d_ws;
  u16*   hs_bf   = (u16*)(p + 0);                    // 12.58 MB, dead after gemm v
  u16*   vTb     = (u16*)(p + 0);                    // 4.19 MB (after hs_bf dead)
  u16*   mean_bf = (u16*)(p + 4194304);              // 4.19 MB
  u16*   WqT     = (u16*)(p + 12582912);             // 18.87 MB, dead after gemm q
  float* gram    = (float*)(p + 12582912);           // 8.39 MB  (after WqT dead)
  u16*   WoT     = (u16*)(p + 12582912);             // 6.29 MB  (after gram dead)
  float* meanf   = (float*)(p + 12582912 + 8388608); // 8.39 MB
  u16*   WkT     = (u16*)(p + 31457280);             // 6.29 MB
  u16*   WvT     = WkT;
  u16*   WqkT    = (u16*)(p + 37748736);             // 0.20 MB
  u16*   q_bf    = (u16*)(p + 37945344);             // 12.58 MB
  u16*   k_bf    = (u16*)(p + 50528256);             // 4.19 MB
  u16*   v_bf    = (u16*)(p + 54722560);             // 4.19 MB
  float* nrmA    = (float*)(p + 58916864);           // 8 KB
  unsigned char* rowAnyA = (unsigned char*)(p + 58925056); // 2 KB
  int*   anyCnt  = (int*)(p + 58927104);             // 8 B
  if (ws_size < 58931200) return;

  const dim3 tb(32, 8);

  k_cvt_bf16<<<6144, 256, 0, stream>>>(hs, hs_bf, BATCH * SEQ * DIM / 4);
  k_tr_f32_bf16<<<dim3(96, 96), tb, 0, stream>>>(Wq, WqT, DIM, DIM);
  k_gemm_bt<true, true><<<dim3(16 * 24, 1), 256, 0, stream>>>(hs_bf, WqT, q_bf, bq, 2048, DIM, DIM, 0, 0, 0);
  k_tr_f32_bf16<<<dim3(32, 96), tb, 0, stream>>>(Wk, WkT, DIM, KDIM);
  k_gemm_bt<true, true><<<dim3(16 * 8, 1), 256, 0, stream>>>(hs_bf, WkT, k_bf, bk, 2048, KDIM, DIM, 0, 0, 0);
  k_gemm_bt<false, false><<<dim3(8 * 8, 2), 256, 0, stream>>>(k_bf, k_bf, gram, nullptr, SEQ, SEQ, KDIM,
                                                              (long long)SEQ * KDIM, (long long)SEQ * KDIM,
                                                              (long long)SEQ * SEQ);
  k_norms<<<2, 1024, 0, stream>>>(gram, nrmA, anyCnt);
  k_rowany<<<dim3(SEQ, 2), 256, 0, stream>>>(gram, nrmA, rowAnyA, anyCnt);
  k_scan_replace<<<2, 1024, 0, stream>>>(gram, nrmA, rowAnyA, anyCnt, k_bf);
  k_tr_f32_bf16<<<dim3(32, 96), tb, 0, stream>>>(Wv, WvT, DIM, KDIM);
  k_gemm_bt<true, true><<<dim3(16 * 8, 1), 256, 0, stream>>>(hs_bf, WvT, v_bf, bv, 2048, KDIM, DIM, 0, 0, 0);
  k_gemm_bt<false, false><<<dim3(8 * 8, 2), 256, 0, stream>>>(v_bf, v_bf, gram, nullptr, SEQ, SEQ, KDIM,
                                                              (long long)SEQ * KDIM, (long long)SEQ * KDIM,
                                                              (long long)SEQ * SEQ);
  k_norms<<<2, 1024, 0, stream>>>(gram, nrmA, anyCnt);
  k_rowany<<<dim3(SEQ, 2), 256, 0, stream>>>(gram, nrmA, rowAnyA, anyCnt);
  k_scan_replace<<<2, 1024, 0, stream>>>(gram, nrmA, rowAnyA, anyCnt, v_bf);
  k_tr_f32_bf16<<<dim3(96, 32), tb, 0, stream>>>(Wo, WoT, KDIM, DIM);
  k_tr_bf16<<<dim3(32, 32, 2), tb, 0, stream>>>(v_bf, vTb, SEQ, KDIM);
  k_tr_f32_bf16<<<dim3(32, 3), tb, 0, stream>>>(Wqk, WqkT, HDQ, KDIM);
  hipMemsetAsync(meanf, 0, (size_t)BATCH * SEQ * KDIM * sizeof(float), stream);
  k_attn<<<512, 512, 0, stream>>>(q_bf, k_bf, vTb, WqkT, bqk, meanf);
  k_cvt_bf16<<<2048, 256, 0, stream>>>(meanf, mean_bf, BATCH * SEQ * KDIM / 4);
  k_gemm_bt<false, true><<<dim3(16 * 24, 1), 256, 0, stream>>>(mean_bf, WoT, (float*)d_out, bo, 2048, DIM, KDIM, 0, 0, 0);
}

// Round 3
// 386.513 us; speedup vs baseline: 5.5048x; 4.0564x over previous
//
#include <hip/hip_runtime.h>
#include <hip/hip_bf16.h>
#include <stdint.h>

#define BATCH 2
#define SEQ   1024
#define DIM   3072
#define KDIM  1024
#define NHEAD 32
#define HDQ   96
#define THR_SIM 0.95f

typedef unsigned short u16;
typedef __attribute__((ext_vector_type(8))) short short8;
typedef __attribute__((ext_vector_type(4))) float f32x4;

__device__ __forceinline__ u16 f2bf(float f) {
  union { float f; unsigned u; } v; v.f = f;
  unsigned r = v.u + 0x7FFFu + ((v.u >> 16) & 1u);
  return (u16)(r >> 16);
}
__device__ __forceinline__ float bf2f(u16 x) {
  union { unsigned u; float f; } v; v.u = ((unsigned)x) << 16; return v.f;
}

__device__ __forceinline__ f32x4 mfma16(short8 a, short8 b, f32x4 c) {
  return __builtin_amdgcn_mfma_f32_16x16x32_bf16(a, b, c, 0, 0, 0);
}

// ---------------- fp32 -> bf16 convert (vectorized) ----------------
__global__ void k_cvt_bf16(const float* __restrict__ in, u16* __restrict__ out, int n4) {
  int i = blockIdx.x * blockDim.x + threadIdx.x;
  if (i < n4) {
    float4 v = ((const float4*)in)[i];
    ushort4 o;
    o.x = f2bf(v.x); o.y = f2bf(v.y); o.z = f2bf(v.z); o.w = f2bf(v.w);
    ((ushort4*)out)[i] = o;
  }
}

// ---------------- transpose fp32 (R,C) -> bf16 (C,R) ----------------
__global__ void k_tr_f32_bf16(const float* __restrict__ in, u16* __restrict__ out, int R, int C) {
  __shared__ float t[32][33];
  int c0 = blockIdx.x * 32, r0 = blockIdx.y * 32;
  int tx = threadIdx.x, ty = threadIdx.y; // (32,8)
  #pragma unroll
  for (int k = 0; k < 4; ++k)
    t[ty + 8 * k][tx] = in[(size_t)(r0 + ty + 8 * k) * C + c0 + tx];
  __syncthreads();
  #pragma unroll
  for (int k = 0; k < 4; ++k)
    out[(size_t)(c0 + ty + 8 * k) * R + r0 + tx] = f2bf(t[tx][ty + 8 * k]);
}

// ---------------- transpose bf16 (R,C) -> bf16 (C,R), batched over z ----------------
__global__ void k_tr_bf16(const u16* __restrict__ in, u16* __restrict__ out, int R, int C) {
  __shared__ u16 t[32][33];
  size_t base = (size_t)blockIdx.z * R * C;
  int c0 = blockIdx.x * 32, r0 = blockIdx.y * 32;
  int tx = threadIdx.x, ty = threadIdx.y;
  #pragma unroll
  for (int k = 0; k < 4; ++k)
    t[ty + 8 * k][tx] = in[base + (size_t)(r0 + ty + 8 * k) * C + c0 + tx];
  __syncthreads();
  #pragma unroll
  for (int k = 0; k < 4; ++k)
    out[base + (size_t)(c0 + ty + 8 * k) * R + r0 + tx] = t[tx][ty + 8 * k];
}

// ---------------- build extended Wqk operand: rows 0..95 = Wqk, row 96 = bqk, 97..127 = 0 ----------------
__global__ void k_build_wqke(const float* __restrict__ Wqk, const float* __restrict__ bqk,
                             u16* __restrict__ out) {
  const int n = blockIdx.x;           // 0..127
  const int c = threadIdx.x * 4;      // 256 threads x 4
  float4 v;
  if (n < 96)       v = *(const float4*)(Wqk + (size_t)n * KDIM + c);
  else if (n == 96) v = *(const float4*)(bqk + c);
  else              v = make_float4(0.f, 0.f, 0.f, 0.f);
  ushort4 o;
  o.x = f2bf(v.x); o.y = f2bf(v.y); o.z = f2bf(v.z); o.w = f2bf(v.w);
  *(ushort4*)(out + (size_t)n * KDIM + c) = o;
}

// ---------------- GEMM: C(M,N) = A(M,K) @ Bt(N,K)^T (+bias[N]) ----------------
template<bool OUT_BF16, bool BIAS>
__global__ __launch_bounds__(256, 2) void k_gemm_bt(
    const u16* __restrict__ A, const u16* __restrict__ Bt, void* __restrict__ Cv,
    const float* __restrict__ bias, int M, int N, int K,
    long long bsA, long long bsB, long long bsC)
{
  const int zb = blockIdx.y;
  A  += (size_t)zb * bsA;
  Bt += (size_t)zb * bsB;
  u16*   Cb16 = (u16*)Cv + (size_t)zb * bsC;
  float* Cf32 = (float*)Cv + (size_t)zb * bsC;

  __shared__ u16 As[128 * 32];
  __shared__ u16 Bs[128 * 32];
  const int nt = N >> 7;
  const int tm = blockIdx.x / nt, tn = blockIdx.x % nt;
  const int tid = threadIdx.x, lane = tid & 63, wid = tid >> 6;
  const int wr = wid >> 1, wc = wid & 1, li = lane & 15, lg = lane >> 4;

  const int srow = tid >> 2, scol = (tid & 3) * 8;
  const u16* gA0 = A + (size_t)(tm * 128 + srow) * K + scol;
  const u16* gA1 = gA0 + (size_t)64 * K;
  const u16* gB0 = Bt + (size_t)(tn * 128 + srow) * K + scol;
  const u16* gB1 = gB0 + (size_t)64 * K;
  u16* sA0 = As + srow * 32 + scol; u16* sA1 = sA0 + 64 * 32;
  u16* sB0 = Bs + srow * 32 + scol; u16* sB1 = sB0 + 64 * 32;

  f32x4 acc[4][4];
  #pragma unroll
  for (int a = 0; a < 4; ++a)
    #pragma unroll
    for (int b = 0; b < 4; ++b) acc[a][b] = (f32x4){0.f, 0.f, 0.f, 0.f};

  uint4 ra0 = *(const uint4*)gA0, ra1 = *(const uint4*)gA1;
  uint4 rb0 = *(const uint4*)gB0, rb1 = *(const uint4*)gB1;
  const int nk = K >> 5;
  for (int kt = 0; kt < nk; ++kt) {
    __syncthreads();
    *(uint4*)sA0 = ra0; *(uint4*)sA1 = ra1;
    *(uint4*)sB0 = rb0; *(uint4*)sB1 = rb1;
    __syncthreads();
    if (kt + 1 < nk) {
      const int k0 = (kt + 1) << 5;
      ra0 = *(const uint4*)(gA0 + k0); ra1 = *(const uint4*)(gA1 + k0);
      rb0 = *(const uint4*)(gB0 + k0); rb1 = *(const uint4*)(gB1 + k0);
    }
    short8 af[4], bfv[4];
    #pragma unroll
    for (int mf = 0; mf < 4; ++mf)
      af[mf] = *(const short8*)(As + (wr * 64 + mf * 16 + li) * 32 + lg * 8);
    #pragma unroll
    for (int nf = 0; nf < 4; ++nf)
      bfv[nf] = *(const short8*)(Bs + (wc * 64 + nf * 16 + li) * 32 + lg * 8);
    #pragma unroll
    for (int mf = 0; mf < 4; ++mf)
      #pragma unroll
      for (int nf = 0; nf < 4; ++nf)
        acc[mf][nf] = mfma16(af[mf], bfv[nf], acc[mf][nf]);
  }
  #pragma unroll
  for (int mf = 0; mf < 4; ++mf) {
    #pragma unroll
    for (int nf = 0; nf < 4; ++nf) {
      const int col = tn * 128 + wc * 64 + nf * 16 + li;
      const float bb = BIAS ? bias[col] : 0.f;
      #pragma unroll
      for (int j = 0; j < 4; ++j) {
        const int row = tm * 128 + wr * 64 + mf * 16 + lg * 4 + j;
        const float v = acc[mf][nf][j] + bb;
        if (OUT_BF16) Cb16[(size_t)row * N + col] = f2bf(v);
        else          Cf32[(size_t)row * N + col] = v;
      }
    }
  }
}

// ---------------- token replacement: norms, rowAny (parallel), scan+gather ----------------
__global__ void k_norms(const float* __restrict__ gram, float* __restrict__ nrm,
                        int* __restrict__ anyCnt) {
  const int b = blockIdx.x, j = threadIdx.x;
  const float* g = gram + (size_t)b * SEQ * SEQ;
  float nj = fmaxf(sqrtf(fmaxf(g[(size_t)j * SEQ + j], 0.f)), 1e-8f);
  nrm[b * SEQ + j] = nj;
  if (j == 0) anyCnt[b] = 0;
}

__global__ void k_rowany(const float* __restrict__ gram, const float* __restrict__ nrm,
                         unsigned char* __restrict__ rowAny, int* __restrict__ anyCnt) {
  const int i = blockIdx.x, b = blockIdx.y, t = threadIdx.x; // 256 threads
  const float* g = gram + (size_t)b * SEQ * SEQ + (size_t)i * SEQ;
  const float* nr = nrm + b * SEQ;
  const float ni = nr[i];
  int any = 0;
  for (int j = i + 1 + t; j < SEQ; j += 256)
    any |= (g[j] > THR_SIM * ni * nr[j]) ? 1 : 0;
  any = __any(any) ? 1 : 0;
  __shared__ int s[4];
  if ((t & 63) == 0) s[t >> 6] = any;
  __syncthreads();
  if (t == 0) {
    int a = s[0] | s[1] | s[2] | s[3];
    rowAny[b * SEQ + i] = (unsigned char)a;
    if (a) atomicAdd(&anyCnt[b], 1);
  }
}

__global__ __launch_bounds__(1024) void k_scan_replace(
    const float* __restrict__ gram, const float* __restrict__ nrmG,
    const unsigned char* __restrict__ rowAnyG, const int* __restrict__ anyCnt,
    u16* __restrict__ data)
{
  const int b = blockIdx.x;
  if (anyCnt[b] == 0) return;  // block-uniform fast path
  const float* g = gram + (size_t)b * SEQ * SEQ;
  u16* dat = data + (size_t)b * SEQ * KDIM;
  __shared__ float nrm[SEQ];
  __shared__ unsigned char used[SEQ];
  __shared__ unsigned char rowAny[SEQ];
  __shared__ short rep[SEQ];
  const int j = threadIdx.x;
  nrm[j] = nrmG[b * SEQ + j];
  rowAny[j] = rowAnyG[b * SEQ + j];
  used[j] = 0; rep[j] = (short)j;
  __syncthreads();
  for (int i = 0; i < SEQ - 1; ++i) {
    if (rowAny[i] && !used[i]) {
      const float t = THR_SIM * nrm[i];
      if (j > i && !used[j] && g[(size_t)i * SEQ + j] > t * nrm[j]) {
        used[j] = 1; rep[j] = (short)i;
      }
      __syncthreads();
    }
  }
  __syncthreads();
  const int src = rep[j];
  if (src != j) {
    for (int c = 0; c < KDIM; c += 8)
      *(uint4*)(dat + (size_t)j * KDIM + c) = *(const uint4*)(dat + (size_t)src * KDIM + c);
  }
}

// ---------------- attention probabilities, mean over heads (partial per head-group) ----------------
// scores[s,t] = (q[s,:96] . KKT[t,:96] + bkk[t]) / 32;  Pbar_part[pg] = sum_{h in pg} softmax_row / 32.
// grid 256 = xcd(8: b x pg) x 32 q-tiles. 512 threads (8 waves); wave w owns keys [w*128,+128).
__global__ __launch_bounds__(512) void k_attn2(
    const u16* __restrict__ q_bf, const u16* __restrict__ KKTe,
    u16* __restrict__ pbar_part)
{
  const int bid = blockIdx.x;
  const int xcd = bid & 7, idx = bid >> 3;
  const int b = xcd >> 2;          // batch fixed per XCD-half
  const int pg = xcd & 3;          // head-group: heads pg*8 .. pg*8+7
  const int q0 = idx * 32;
  const int tid = threadIdx.x, lane = tid & 63, w = tid >> 6;
  const int li = lane & 15, lg = lane >> 4;

  __shared__ u16 qs[32 * 104];     // padded stride (208B = 13x16B, bank-friendly)
  __shared__ float bkkl[1024];
  __shared__ float red[8 * 32];
  __shared__ float gmax[32];
  __shared__ float ginv[32];

  const u16* KKb = KKTe + (size_t)b * SEQ * 128;
  for (int i = tid; i < 1024; i += 512)
    bkkl[i] = bf2f(KKb[(size_t)i * 128 + 96]);

  f32x4 accm[2][8];
  #pragma unroll
  for (int mf = 0; mf < 2; ++mf)
    #pragma unroll
    for (int nf = 0; nf < 8; ++nf) accm[mf][nf] = (f32x4){0.f, 0.f, 0.f, 0.f};

  for (int hh = 0; hh < 8; ++hh) {
    const int h = pg * 8 + hh;
    __syncthreads();
    if (tid < 384) {
      const int row = tid / 12, cc = (tid % 12) * 8;
      *(uint4*)(qs + row * 104 + cc) =
          *(const uint4*)(q_bf + ((size_t)(b * SEQ + q0 + row)) * DIM + h * HDQ + cc);
    }
    __syncthreads();

    // ---- scores: M=32 rows, K=96, wave w covers keys [w*128,+128) ----
    f32x4 acc2[2][8];
    #pragma unroll
    for (int mf = 0; mf < 2; ++mf)
      #pragma unroll
      for (int nf = 0; nf < 8; ++nf) acc2[mf][nf] = (f32x4){0.f, 0.f, 0.f, 0.f};
    #pragma unroll
    for (int ks = 0; ks < 3; ++ks) {
      short8 a0 = *(const short8*)(qs + li * 104 + ks * 32 + lg * 8);
      short8 a1 = *(const short8*)(qs + (16 + li) * 104 + ks * 32 + lg * 8);
      #pragma unroll
      for (int nf = 0; nf < 8; ++nf) {
        short8 bb = *(const short8*)(KKb + (size_t)(w * 128 + nf * 16 + li) * 128 + ks * 32 + lg * 8);
        acc2[0][nf] = mfma16(a0, bb, acc2[0][nf]);
        acc2[1][nf] = mfma16(a1, bb, acc2[1][nf]);
      }
    }
    #pragma unroll
    for (int nf = 0; nf < 8; ++nf) {
      const float bb = bkkl[w * 128 + nf * 16 + li];
      #pragma unroll
      for (int mf = 0; mf < 2; ++mf)
        #pragma unroll
        for (int jj = 0; jj < 4; ++jj)
          acc2[mf][nf][jj] = (acc2[mf][nf][jj] + bb) * 0.03125f;
    }

    // ---- softmax over all 1024 keys ----
    float rmax[2][4];
    #pragma unroll
    for (int mf = 0; mf < 2; ++mf)
      #pragma unroll
      for (int jj = 0; jj < 4; ++jj) {
        float m = -1e30f;
        #pragma unroll
        for (int nf = 0; nf < 8; ++nf) m = fmaxf(m, acc2[mf][nf][jj]);
        rmax[mf][jj] = m;
      }
    #pragma unroll
    for (int d2 = 1; d2 < 16; d2 <<= 1)
      #pragma unroll
      for (int mf = 0; mf < 2; ++mf)
        #pragma unroll
        for (int jj = 0; jj < 4; ++jj)
          rmax[mf][jj] = fmaxf(rmax[mf][jj], __shfl_xor(rmax[mf][jj], d2));
    if (li == 0) {
      #pragma unroll
      for (int mf = 0; mf < 2; ++mf)
        #pragma unroll
        for (int jj = 0; jj < 4; ++jj)
          red[w * 32 + mf * 16 + lg * 4 + jj] = rmax[mf][jj];
    }
    __syncthreads();
    if (tid < 32) {
      float m = red[tid];
      #pragma unroll
      for (int ww = 1; ww < 8; ++ww) m = fmaxf(m, red[ww * 32 + tid]);
      gmax[tid] = m;
    }
    __syncthreads();
    float gm[2][4];
    #pragma unroll
    for (int mf = 0; mf < 2; ++mf)
      #pragma unroll
      for (int jj = 0; jj < 4; ++jj) gm[mf][jj] = gmax[mf * 16 + lg * 4 + jj];
    float rsum[2][4] = {{0.f,0.f,0.f,0.f},{0.f,0.f,0.f,0.f}};
    #pragma unroll
    for (int mf = 0; mf < 2; ++mf)
      #pragma unroll
      for (int nf = 0; nf < 8; ++nf)
        #pragma unroll
        for (int jj = 0; jj < 4; ++jj) {
          float pv = __expf(acc2[mf][nf][jj] - gm[mf][jj]);
          acc2[mf][nf][jj] = pv;
          rsum[mf][jj] += pv;
        }
    #pragma unroll
    for (int d2 = 1; d2 < 16; d2 <<= 1)
      #pragma unroll
      for (int mf = 0; mf < 2; ++mf)
        #pragma unroll
        for (int jj = 0; jj < 4; ++jj)
          rsum[mf][jj] += __shfl_xor(rsum[mf][jj], d2);
    if (li == 0) {
      #pragma unroll
      for (int mf = 0; mf < 2; ++mf)
        #pragma unroll
        for (int jj = 0; jj < 4; ++jj)
          red[w * 32 + mf * 16 + lg * 4 + jj] = rsum[mf][jj];
    }
    __syncthreads();
    if (tid < 32) {
      float s2 = 0.f;
      #pragma unroll
      for (int ww = 0; ww < 8; ++ww) s2 += red[ww * 32 + tid];
      ginv[tid] = 1.f / (32.f * s2);
    }
    __syncthreads();
    float gi[2][4];
    #pragma unroll
    for (int mf = 0; mf < 2; ++mf)
      #pragma unroll
      for (int jj = 0; jj < 4; ++jj) gi[mf][jj] = ginv[mf * 16 + lg * 4 + jj];
    #pragma unroll
    for (int mf = 0; mf < 2; ++mf)
      #pragma unroll
      for (int nf = 0; nf < 8; ++nf)
        #pragma unroll
        for (int jj = 0; jj < 4; ++jj)
          accm[mf][nf][jj] += acc2[mf][nf][jj] * gi[mf][jj];
  } // heads

  // one-shot write of this head-group's partial Pbar (bf16), no atomics
  u16* dst = pbar_part + ((size_t)(pg * 2 + b) * SEQ) * SEQ;
  #pragma unroll
  for (int mf = 0; mf < 2; ++mf)
    #pragma unroll
    for (int nf = 0; nf < 8; ++nf)
      #pragma unroll
      for (int jj = 0; jj < 4; ++jj) {
        const int row = q0 + mf * 16 + lg * 4 + jj;
        const int col = w * 128 + nf * 16 + li;
        dst[(size_t)row * SEQ + col] = f2bf(accm[mf][nf][jj]);
      }
}

// ---------------- reduce 4 Pbar partials -> bf16 Pbar ----------------
__global__ void k_reduce_pbar(const u16* __restrict__ part, u16* __restrict__ out) {
  const size_t N = (size_t)BATCH * SEQ * SEQ;
  size_t i = (size_t)blockIdx.x * blockDim.x + threadIdx.x; // 8-elem chunk
  if (i >= N / 8) return;
  short8 p0 = ((const short8*)part)[i];
  short8 p1 = ((const short8*)(part + N))[i];
  short8 p2 = ((const short8*)(part + 2 * N))[i];
  short8 p3 = ((const short8*)(part + 3 * N))[i];
  short8 o;
  #pragma unroll
  for (int j = 0; j < 8; ++j) {
    float s = bf2f((u16)p0[j]) + bf2f((u16)p1[j]) + bf2f((u16)p2[j]) + bf2f((u16)p3[j]);
    o[j] = (short)f2bf(s);
  }
  ((short8*)out)[i] = o;
}

// ---------------- host ----------------
extern "C" void kernel_launch(void* const* d_in, const int* in_sizes, int n_in,
                              void* d_out, int out_size, void* d_ws, size_t ws_size,
                              hipStream_t stream)
{
  (void)in_sizes; (void)n_in; (void)out_size;
  const float* hs  = (const float*)d_in[0];
  const float* Wq  = (const float*)d_in[1];
  const float* bq  = (const float*)d_in[2];
  const float* Wk  = (const float*)d_in[3];
  const float* bk  = (const float*)d_in[4];
  const float* Wv  = (const float*)d_in[5];
  const float* bv  = (const float*)d_in[6];
  const float* Wqk = (const float*)d_in[7];
  const float* bqk = (const float*)d_in[8];
  const float* Wo  = (const float*)d_in[9];
  const float* bo  = (const float*)d_in[10];

  // workspace layout (sequential lifetimes):
  // [0,12.58M)      hs_bf (dead after v GEMM)          -> pbar_part [0,16.78M) from attn2 on
  // [12.58M,31.46M) WqT (dead after q GEMM) -> gram [12.58M,20.97M) + nrm/rowany/anyCnt
  //                 -> (post v-scan) WqkE/KKTe/Pbar_bf/pv_out/vTb
  // [31.46M,44.04M) q_bf ; [44.04M,48.23M) k_bf ; [48.23M,52.43M) v_bf
  // [52.43M,58.72M) WkT -> WvT -> WoT
  char* p = (char*)d_ws;
  u16*   hs_bf   = (u16*)(p + 0);
  u16*   pbarP   = (u16*)(p + 0);                  // 16,777,216 B
  u16*   WqT     = (u16*)(p + 12582912);
  float* gram    = (float*)(p + 12582912);         // 8,388,608 B
  float* nrmA    = (float*)(p + 20971520);         // 8 KB
  unsigned char* rowAnyA = (unsigned char*)(p + 20979712); // 2 KB
  int*   anyCnt  = (int*)(p + 20981760);           // 16 B
  u16*   WqkE    = (u16*)(p + 16777216);           // 262,144 B (post v-scan)
  u16*   KKTe    = (u16*)(p + 17039360);           // 524,288 B
  u16*   Pbar_bf = (u16*)(p + 17563648);           // 4,194,304 B
  u16*   pv_out  = (u16*)(p + 21757952);           // 4,194,304 B
  u16*   vTb     = (u16*)(p + 25952256);           // 4,194,304 B
  u16*   q_bf    = (u16*)(p + 31457280);           // 12,582,912 B
  u16*   k_bf    = (u16*)(p + 44040192);           // 4,194,304 B
  u16*   v_bf    = (u16*)(p + 48234496);           // 4,194,304 B
  u16*   WkT     = (u16*)(p + 52428800);           // 6,291,456 B
  u16*   WvT     = WkT;
  u16*   WoT     = WkT;
  if (ws_size < 58720256) return;

  const dim3 tb(32, 8);

  // projections
  k_cvt_bf16<<<6144, 256, 0, stream>>>(hs, hs_bf, BATCH * SEQ * DIM / 4);
  k_tr_f32_bf16<<<dim3(96, 96), tb, 0, stream>>>(Wq, WqT, DIM, DIM);
  k_gemm_bt<true, true><<<dim3(16 * 24, 1), 256, 0, stream>>>(hs_bf, WqT, q_bf, bq, 2048, DIM, DIM, 0, 0, 0);
  k_tr_f32_bf16<<<dim3(32, 96), tb, 0, stream>>>(Wk, WkT, DIM, KDIM);
  k_gemm_bt<true, true><<<dim3(16 * 8, 1), 256, 0, stream>>>(hs_bf, WkT, k_bf, bk, 2048, KDIM, DIM, 0, 0, 0);
  // k replacement
  k_gemm_bt<false, false><<<dim3(8 * 8, 2), 256, 0, stream>>>(k_bf, k_bf, gram, nullptr, SEQ, SEQ, KDIM,
                                                              (long long)SEQ * KDIM, (long long)SEQ * KDIM,
                                                              (long long)SEQ * SEQ);
  k_norms<<<2, 1024, 0, stream>>>(gram, nrmA, anyCnt);
  k_rowany<<<dim3(SEQ, 2), 256, 0, stream>>>(gram, nrmA, rowAnyA, anyCnt);
  k_scan_replace<<<2, 1024, 0, stream>>>(gram, nrmA, rowAnyA, anyCnt, k_bf);
  // v projection + replacement
  k_tr_f32_bf16<<<dim3(32, 96), tb, 0, stream>>>(Wv, WvT, DIM, KDIM);
  k_gemm_bt<true, true><<<dim3(16 * 8, 1), 256, 0, stream>>>(hs_bf, WvT, v_bf, bv, 2048, KDIM, DIM, 0, 0, 0);
  k_gemm_bt<false, false><<<dim3(8 * 8, 2), 256, 0, stream>>>(v_bf, v_bf, gram, nullptr, SEQ, SEQ, KDIM,
                                                              (long long)SEQ * KDIM, (long long)SEQ * KDIM,
                                                              (long long)SEQ * SEQ);
  k_norms<<<2, 1024, 0, stream>>>(gram, nrmA, anyCnt);
  k_rowany<<<dim3(SEQ, 2), 256, 0, stream>>>(gram, nrmA, rowAnyA, anyCnt);
  k_scan_replace<<<2, 1024, 0, stream>>>(gram, nrmA, rowAnyA, anyCnt, v_bf);
  // KKT = K_new @ [Wqk;bqk;0]^T  (per batch, N=128 cols: 0..95 = dims, 96 = bias row)
  k_build_wqke<<<128, 256, 0, stream>>>(Wqk, bqk, WqkE);
  k_gemm_bt<true, false><<<dim3(8, 2), 256, 0, stream>>>(k_bf, WqkE, KKTe, nullptr, SEQ, 128, KDIM,
                                                         (long long)SEQ * KDIM, 0, (long long)SEQ * 128);
  // V^T for the PV GEMM; Wo^T for the final GEMM
  k_tr_bf16<<<dim3(32, 32, 2), tb, 0, stream>>>(v_bf, vTb, SEQ, KDIM);
  k_tr_f32_bf16<<<dim3(96, 32), tb, 0, stream>>>(Wo, WoT, KDIM, DIM);
  // attention probabilities + head-mean (4 head-group partials, no atomics)
  k_attn2<<<256, 512, 0, stream>>>(q_bf, KKTe, pbarP);
  k_reduce_pbar<<<1024, 256, 0, stream>>>(pbarP, Pbar_bf);
  // out_pv = Pbar @ V  (one GEMM per batch)
  k_gemm_bt<true, false><<<dim3(8 * 8, 2), 256, 0, stream>>>(Pbar_bf, vTb, pv_out, nullptr, SEQ, KDIM, SEQ,
                                                             (long long)SEQ * SEQ, (long long)KDIM * SEQ,
                                                             (long long)SEQ * KDIM);
  // final: out = pv_out @ Wo + bo
  k_gemm_bt<false, true><<<dim3(16 * 24, 1), 256, 0, stream>>>(pv_out, WoT, (float*)d_out, bo, 2048, DIM, KDIM, 0, 0, 0);
}

// Round 4
// 335.552 us; speedup vs baseline: 6.3409x; 1.1519x over previous
//
#include <hip/hip_runtime.h>
#include <hip/hip_bf16.h>
#include <stdint.h>

#define BATCH 2
#define SEQ   1024
#define DIM   3072
#define KDIM  1024
#define NHEAD 32
#define HDQ   96
#define THR_SIM 0.95f

typedef unsigned short u16;
typedef __attribute__((ext_vector_type(8))) short short8;
typedef __attribute__((ext_vector_type(4))) float f32x4;

typedef const __attribute__((address_space(1))) unsigned int* gas_ptr;
typedef __attribute__((address_space(3))) unsigned int* las_ptr;

__device__ __forceinline__ void glds16(const u16* g, u16* l) {
  __builtin_amdgcn_global_load_lds((gas_ptr)g, (las_ptr)l, 16, 0, 0);
}

__device__ __forceinline__ u16 f2bf(float f) {
  union { float f; unsigned u; } v; v.f = f;
  unsigned r = v.u + 0x7FFFu + ((v.u >> 16) & 1u);
  return (u16)(r >> 16);
}
__device__ __forceinline__ float bf2f(u16 x) {
  union { unsigned u; float f; } v; v.u = ((unsigned)x) << 16; return v.f;
}

__device__ __forceinline__ f32x4 mfma16(short8 a, short8 b, f32x4 c) {
  return __builtin_amdgcn_mfma_f32_16x16x32_bf16(a, b, c, 0, 0, 0);
}

// ---------------- fp32 -> bf16 convert (vectorized) ----------------
__global__ void k_cvt_bf16(const float* __restrict__ in, u16* __restrict__ out, int n4) {
  int i = blockIdx.x * blockDim.x + threadIdx.x;
  if (i < n4) {
    float4 v = ((const float4*)in)[i];
    ushort4 o;
    o.x = f2bf(v.x); o.y = f2bf(v.y); o.z = f2bf(v.z); o.w = f2bf(v.w);
    ((ushort4*)out)[i] = o;
  }
}

// ---------------- transpose fp32 (R,C) -> bf16 (C,R) ----------------
__global__ void k_tr_f32_bf16(const float* __restrict__ in, u16* __restrict__ out, int R, int C) {
  __shared__ float t[32][33];
  int c0 = blockIdx.x * 32, r0 = blockIdx.y * 32;
  int tx = threadIdx.x, ty = threadIdx.y; // (32,8)
  #pragma unroll
  for (int k = 0; k < 4; ++k)
    t[ty + 8 * k][tx] = in[(size_t)(r0 + ty + 8 * k) * C + c0 + tx];
  __syncthreads();
  #pragma unroll
  for (int k = 0; k < 4; ++k)
    out[(size_t)(c0 + ty + 8 * k) * R + r0 + tx] = f2bf(t[tx][ty + 8 * k]);
}

// ---------------- transpose bf16 (R,C) -> (C,R), strided, batched over z ----------------
__global__ void k_tr_bf16(const u16* __restrict__ in, u16* __restrict__ out,
                          int ldin, int ldout, long long zsIn, long long zsOut) {
  __shared__ u16 t[32][33];
  const u16* ib = in + (size_t)blockIdx.z * zsIn;
  u16* ob = out + (size_t)blockIdx.z * zsOut;
  int c0 = blockIdx.x * 32, r0 = blockIdx.y * 32;
  int tx = threadIdx.x, ty = threadIdx.y;
  #pragma unroll
  for (int k = 0; k < 4; ++k)
    t[ty + 8 * k][tx] = ib[(size_t)(r0 + ty + 8 * k) * ldin + c0 + tx];
  __syncthreads();
  #pragma unroll
  for (int k = 0; k < 4; ++k)
    ob[(size_t)(c0 + ty + 8 * k) * ldout + r0 + tx] = t[tx][ty + 8 * k];
}

// ---------------- build extended Wqk operand: rows 0..95 = Wqk, row 96 = bqk, 97..127 = 0 ----------------
__global__ void k_build_wqke(const float* __restrict__ Wqk, const float* __restrict__ bqk,
                             u16* __restrict__ out) {
  const int n = blockIdx.x;           // 0..127
  const int c = threadIdx.x * 4;      // 256 threads x 4
  float4 v;
  if (n < 96)       v = *(const float4*)(Wqk + (size_t)n * KDIM + c);
  else if (n == 96) v = *(const float4*)(bqk + c);
  else              v = make_float4(0.f, 0.f, 0.f, 0.f);
  ushort4 o;
  o.x = f2bf(v.x); o.y = f2bf(v.y); o.z = f2bf(v.z); o.w = f2bf(v.w);
  *(ushort4*)(out + (size_t)n * KDIM + c) = o;
}

// ---------------- concat bk|bv ----------------
__global__ void k_bkv(const float* __restrict__ bk, const float* __restrict__ bv,
                      float* __restrict__ out) {
  int i = blockIdx.x * 256 + threadIdx.x;
  if (i < 2048) out[i] = (i < 1024) ? bk[i] : bv[i - 1024];
}

// ---------------- GEMM: C = A(M,K;lda) @ Bt(N,K;ldb)^T (+bias[N]), m97-style glds staging ----------------
// batch offsets: off = (zb>>1)*bsH + (zb&1)*bsL  for A, B, C.
template<bool OUT_BF16, bool BIAS>
__global__ __launch_bounds__(256, 4) void k_gemm_bt(
    const u16* __restrict__ A, const u16* __restrict__ Bt, void* __restrict__ Cv,
    const float* __restrict__ bias, int M, int N, int K,
    int lda, int ldb, int ldc,
    long long bsAH, long long bsAL, long long bsBH, long long bsBL,
    long long bsCH, long long bsCL)
{
  const int zb = blockIdx.y, zH = zb >> 1, zL = zb & 1;
  A  += (size_t)(zH * bsAH + zL * bsAL);
  Bt += (size_t)(zH * bsBH + zL * bsBL);
  u16*   Cb16 = (u16*)Cv + (size_t)(zH * bsCH + zL * bsCL);
  float* Cf32 = (float*)Cv + (size_t)(zH * bsCH + zL * bsCL);

  __shared__ u16 As[2][128 * 32];
  __shared__ u16 Bs[2][128 * 32];
  const int nt = N >> 7;
  const int tm = blockIdx.x / nt, tn = blockIdx.x % nt;
  const int tid = threadIdx.x, lane = tid & 63, wid = tid >> 6;
  const int wr = wid >> 1, wc = wid & 1, li = lane & 15, lg = lane >> 4;

  const int srow = tid >> 2, scol = (tid & 3) * 8;
  const u16* gA0 = A + (size_t)(tm * 128 + srow) * lda + scol;
  const u16* gA1 = gA0 + (size_t)64 * lda;
  const u16* gB0 = Bt + (size_t)(tn * 128 + srow) * ldb + scol;
  const u16* gB1 = gB0 + (size_t)64 * ldb;
  const int wof = wid * 512;   // wave-uniform LDS chunk (64 lanes x 8 elems)

  f32x4 acc[4][4];
  #pragma unroll
  for (int a = 0; a < 4; ++a)
    #pragma unroll
    for (int b = 0; b < 4; ++b) acc[a][b] = (f32x4){0.f, 0.f, 0.f, 0.f};

  const int nk = K >> 5;
  // prologue: stage tile 0 into buf 0
  glds16(gA0, As[0] + wof);
  glds16(gA1, As[0] + 2048 + wof);
  glds16(gB0, Bs[0] + wof);
  glds16(gB1, Bs[0] + 2048 + wof);
  __syncthreads();

  int cur = 0;
  for (int kt = 0; kt < nk; ++kt) {
    if (kt + 1 < nk) {
      const int k0 = (kt + 1) << 5;
      glds16(gA0 + k0, As[cur ^ 1] + wof);
      glds16(gA1 + k0, As[cur ^ 1] + 2048 + wof);
      glds16(gB0 + k0, Bs[cur ^ 1] + wof);
      glds16(gB1 + k0, Bs[cur ^ 1] + 2048 + wof);
    }
    short8 af[4], bfv[4];
    #pragma unroll
    for (int mf = 0; mf < 4; ++mf)
      af[mf] = *(const short8*)(As[cur] + (wr * 64 + mf * 16 + li) * 32 + lg * 8);
    #pragma unroll
    for (int nf = 0; nf < 4; ++nf)
      bfv[nf] = *(const short8*)(Bs[cur] + (wc * 64 + nf * 16 + li) * 32 + lg * 8);
    #pragma unroll
    for (int mf = 0; mf < 4; ++mf)
      #pragma unroll
      for (int nf = 0; nf < 4; ++nf)
        acc[mf][nf] = mfma16(af[mf], bfv[nf], acc[mf][nf]);
    __syncthreads();
    cur ^= 1;
  }
  #pragma unroll
  for (int mf = 0; mf < 4; ++mf) {
    #pragma unroll
    for (int nf = 0; nf < 4; ++nf) {
      const int col = tn * 128 + wc * 64 + nf * 16 + li;
      const float bb = BIAS ? bias[col] : 0.f;
      #pragma unroll
      for (int j = 0; j < 4; ++j) {
        const int row = tm * 128 + wr * 64 + mf * 16 + lg * 4 + j;
        const float v = acc[mf][nf][j] + bb;
        if (OUT_BF16) Cb16[(size_t)row * ldc + col] = f2bf(v);
        else          Cf32[(size_t)row * ldc + col] = v;
      }
    }
  }
}

// ---------------- token replacement: norms, rowAny (parallel), scan+gather ----------------
// 4 slices: s = b*2 + kv; gram slice s at gram + s*SEQ*SEQ; data row view in kv_bf.
__global__ void k_norms(const float* __restrict__ gram, float* __restrict__ nrm,
                        int* __restrict__ anyCnt) {
  const int s = blockIdx.x, j = threadIdx.x;
  const float* g = gram + (size_t)s * SEQ * SEQ;
  float nj = fmaxf(sqrtf(fmaxf(g[(size_t)j * SEQ + j], 0.f)), 1e-8f);
  nrm[s * SEQ + j] = nj;
  if (j == 0) anyCnt[s] = 0;
}

__global__ void k_rowany(const float* __restrict__ gram, const float* __restrict__ nrm,
                         unsigned char* __restrict__ rowAny, int* __restrict__ anyCnt) {
  const int i = blockIdx.x, s = blockIdx.y, t = threadIdx.x; // 256 threads
  const float* g = gram + (size_t)s * SEQ * SEQ + (size_t)i * SEQ;
  const float* nr = nrm + s * SEQ;
  const float ni = nr[i];
  int any = 0;
  for (int j = i + 1 + t; j < SEQ; j += 256)
    any |= (g[j] > THR_SIM * ni * nr[j]) ? 1 : 0;
  any = __any(any) ? 1 : 0;
  __shared__ int sh[4];
  if ((t & 63) == 0) sh[t >> 6] = any;
  __syncthreads();
  if (t == 0) {
    int a = sh[0] | sh[1] | sh[2] | sh[3];
    rowAny[s * SEQ + i] = (unsigned char)a;
    if (a) atomicAdd(&anyCnt[s], 1);
  }
}

__global__ __launch_bounds__(1024) void k_scan_replace(
    const float* __restrict__ gram, const float* __restrict__ nrmG,
    const unsigned char* __restrict__ rowAnyG, const int* __restrict__ anyCnt,
    u16* __restrict__ kvbase)
{
  const int s = blockIdx.x;
  if (anyCnt[s] == 0) return;  // block-uniform fast path
  const float* g = gram + (size_t)s * SEQ * SEQ;
  u16* dat = kvbase + (size_t)(s >> 1) * (2048 * 2048 / 2) * 2 + (size_t)(s & 1) * 1024;
  const int ldr = 2048;
  __shared__ float nrm[SEQ];
  __shared__ unsigned char used[SEQ];
  __shared__ unsigned char rowAny[SEQ];
  __shared__ short rep[SEQ];
  const int j = threadIdx.x;
  nrm[j] = nrmG[s * SEQ + j];
  rowAny[j] = rowAnyG[s * SEQ + j];
  used[j] = 0; rep[j] = (short)j;
  __syncthreads();
  for (int i = 0; i < SEQ - 1; ++i) {
    if (rowAny[i] && !used[i]) {
      const float t = THR_SIM * nrm[i];
      if (j > i && !used[j] && g[(size_t)i * SEQ + j] > t * nrm[j]) {
        used[j] = 1; rep[j] = (short)i;
      }
      __syncthreads();
    }
  }
  __syncthreads();
  const int src = rep[j];
  if (src != j) {
    for (int c = 0; c < KDIM; c += 8)
      *(uint4*)(dat + (size_t)j * ldr + c) = *(const uint4*)(dat + (size_t)src * ldr + c);
  }
}

// ---------------- attention probabilities + head-mean partials ----------------
// Swapped-operand MFMA: A = KKT keys (cached in regs across heads), B = q rows.
// grid 512 = xcd(8: b x pg) x 64 q-tiles of 16 rows. 1024 threads = 16 waves,
// wave w owns keys [w*64, w*64+64). One barrier per head (flash combine, 2 LDS slots).
__global__ __launch_bounds__(1024, 4) void k_attn3(
    const u16* __restrict__ q_bf, const u16* __restrict__ KKTe,
    u16* __restrict__ pbarP)
{
  const int bid = blockIdx.x;
  const int xcd = bid & 7, qt = bid >> 3;
  const int b = xcd >> 2, pg = xcd & 3;
  const int q0 = qt * 16;
  const int tid = threadIdx.x, lane = tid & 63, w = tid >> 6;
  const int li = lane & 15, lg = lane >> 4;

  __shared__ float bkkl[1024];
  __shared__ float2 red[2][16][16];

  const u16* KKb = KKTe + (size_t)b * SEQ * 128;
  bkkl[tid] = bf2f(KKb[(size_t)tid * 128 + 96]);

  short8 ak[4][3];
  #pragma unroll
  for (int kf = 0; kf < 4; ++kf)
    #pragma unroll
    for (int ks = 0; ks < 3; ++ks)
      ak[kf][ks] = *(const short8*)(KKb + (size_t)(w * 64 + kf * 16 + li) * 128 + ks * 32 + lg * 8);

  f32x4 accm[4];
  #pragma unroll
  for (int kf = 0; kf < 4; ++kf) accm[kf] = (f32x4){0.f, 0.f, 0.f, 0.f};
  __syncthreads();

  const u16* qrow = q_bf + (size_t)(b * SEQ + q0 + li) * DIM + pg * 8 * HDQ;

  for (int hh = 0; hh < 8; ++hh) {
    const u16* qp = qrow + hh * HDQ;
    f32x4 acc[4];
    #pragma unroll
    for (int kf = 0; kf < 4; ++kf) acc[kf] = (f32x4){0.f, 0.f, 0.f, 0.f};
    #pragma unroll
    for (int ks = 0; ks < 3; ++ks) {
      short8 bq = *(const short8*)(qp + ks * 32 + lg * 8);
      #pragma unroll
      for (int kf = 0; kf < 4; ++kf)
        acc[kf] = mfma16(ak[kf][ks], bq, acc[kf]);
    }
    // bias + scale, local max over this wave's 64 keys for q-row li
    float m = -1e30f;
    #pragma unroll
    for (int kf = 0; kf < 4; ++kf) {
      f32x4 bb = *(const f32x4*)(bkkl + w * 64 + kf * 16 + lg * 4);
      #pragma unroll
      for (int j = 0; j < 4; ++j) {
        float s = (acc[kf][j] + bb[j]) * 0.03125f;
        acc[kf][j] = s;
        m = fmaxf(m, s);
      }
    }
    m = fmaxf(m, __shfl_xor(m, 16));
    m = fmaxf(m, __shfl_xor(m, 32));
    float ssum = 0.f;
    #pragma unroll
    for (int kf = 0; kf < 4; ++kf)
      #pragma unroll
      for (int j = 0; j < 4; ++j) {
        float pv = __expf(acc[kf][j] - m);
        acc[kf][j] = pv;
        ssum += pv;
      }
    ssum += __shfl_xor(ssum, 16);
    ssum += __shfl_xor(ssum, 32);
    if (lane < 16) red[hh & 1][w][li] = make_float2(m, ssum);
    __syncthreads();
    // combine 16 wave-partials (flash rescale)
    float mg = -1e30f;
    #pragma unroll
    for (int ww = 0; ww < 16; ++ww) mg = fmaxf(mg, red[hh & 1][ww][li].x);
    float Sg = 0.f;
    #pragma unroll
    for (int ww = 0; ww < 16; ++ww) {
      float2 msv = red[hh & 1][ww][li];
      Sg += msv.y * __expf(msv.x - mg);
    }
    const float gi = __expf(m - mg) / (32.f * Sg);
    #pragma unroll
    for (int kf = 0; kf < 4; ++kf)
      #pragma unroll
      for (int j = 0; j < 4; ++j)
        accm[kf][j] += acc[kf][j] * gi;
  }

  u16* dst = pbarP + (size_t)(pg * 2 + b) * SEQ * SEQ + (size_t)(q0 + li) * SEQ + w * 64;
  #pragma unroll
  for (int kf = 0; kf < 4; ++kf) {
    ushort4 o;
    o.x = f2bf(accm[kf][0]); o.y = f2bf(accm[kf][1]);
    o.z = f2bf(accm[kf][2]); o.w = f2bf(accm[kf][3]);
    *(ushort4*)(dst + kf * 16 + lg * 4) = o;
  }
}

// ---------------- reduce 4 Pbar partials -> bf16 Pbar ----------------
__global__ void k_reduce_pbar(const u16* __restrict__ part, u16* __restrict__ out) {
  const size_t N = (size_t)BATCH * SEQ * SEQ;
  size_t i = (size_t)blockIdx.x * blockDim.x + threadIdx.x; // 8-elem chunk
  if (i >= N / 8) return;
  short8 p0 = ((const short8*)part)[i];
  short8 p1 = ((const short8*)(part + N))[i];
  short8 p2 = ((const short8*)(part + 2 * N))[i];
  short8 p3 = ((const short8*)(part + 3 * N))[i];
  short8 o;
  #pragma unroll
  for (int j = 0; j < 8; ++j) {
    float s = bf2f((u16)p0[j]) + bf2f((u16)p1[j]) + bf2f((u16)p2[j]) + bf2f((u16)p3[j]);
    o[j] = (short)f2bf(s);
  }
  ((short8*)out)[i] = o;
}

// ---------------- host ----------------
extern "C" void kernel_launch(void* const* d_in, const int* in_sizes, int n_in,
                              void* d_out, int out_size, void* d_ws, size_t ws_size,
                              hipStream_t stream)
{
  (void)in_sizes; (void)n_in; (void)out_size;
  const float* hs  = (const float*)d_in[0];
  const float* Wq  = (const float*)d_in[1];
  const float* bq  = (const float*)d_in[2];
  const float* Wk  = (const float*)d_in[3];
  const float* bk  = (const float*)d_in[4];
  const float* Wv  = (const float*)d_in[5];
  const float* bv  = (const float*)d_in[6];
  const float* Wqk = (const float*)d_in[7];
  const float* bqk = (const float*)d_in[8];
  const float* Wo  = (const float*)d_in[9];
  const float* bo  = (const float*)d_in[10];

  // workspace layout (sequential lifetimes):
  // [0,12.58M) hs_bf -> gram4 [0,16.78M) (after kv GEMM) -> pbarP [0,16.78M) (after scans)
  // [12.58M,31.46M) WqT -> WkvT [12.58M,25.17M) -> {WqkE,KKTe,vTb,WoT} after kv GEMM
  // [31.46M,44.04M) q_bf ; [44.04M,52.43M) kv_bf -> {Pbar_bf,pv_out}
  // [52.43M,..) smalls
  char* p = (char*)d_ws;
  u16*   hs_bf   = (u16*)(p + 0);
  float* gram4   = (float*)(p + 0);                // 16,777,216 B
  u16*   pbarP   = (u16*)(p + 0);                  // 16,777,216 B
  u16*   WqT     = (u16*)(p + 12582912);           // 18,874,368 B
  u16*   WkvT    = (u16*)(p + 12582912);           // 12,582,912 B
  u16*   WqkE    = (u16*)(p + 16777216);           //    262,144 B
  u16*   KKTe    = (u16*)(p + 17039360);           //    524,288 B
  u16*   vTb     = (u16*)(p + 17563648);           //  4,194,304 B
  u16*   WoT     = (u16*)(p + 21757952);           //  6,291,456 B
  u16*   q_bf    = (u16*)(p + 31457280);           // 12,582,912 B
  u16*   kv_bf   = (u16*)(p + 44040192);           //  8,388,608 B
  u16*   Pbar_bf = (u16*)(p + 44040192);           //  4,194,304 B (after kv dead)
  u16*   pv_out  = (u16*)(p + 48234496);           //  4,194,304 B
  float* bkv     = (float*)(p + 52428800);         //      8,192 B
  float* nrm4    = (float*)(p + 52436992);         //     16,384 B
  unsigned char* rowAny4 = (unsigned char*)(p + 52453376); // 4,096 B
  int*   anyCnt  = (int*)(p + 52457472);           //         16 B
  if (ws_size < 58916864) return;

  const dim3 tb(32, 8);
  const long long SS = (long long)SEQ * SEQ;       // 1,048,576
  const long long KVB = 2048LL * 1024;             // kv batch stride (elems) = 2,097,152

  // hs -> bf16 ; Wq^T ; q = hs @ Wq^T + bq
  k_cvt_bf16<<<6144, 256, 0, stream>>>(hs, hs_bf, BATCH * SEQ * DIM / 4);
  k_tr_f32_bf16<<<dim3(96, 96), tb, 0, stream>>>(Wq, WqT, DIM, DIM);
  k_gemm_bt<true, true><<<dim3(384, 1), 256, 0, stream>>>(hs_bf, WqT, q_bf, bq,
      2048, DIM, DIM, DIM, DIM, DIM, 0, 0, 0, 0, 0, 0);
  // WkvT = [Wk^T ; Wv^T] ; bkv ; kv = hs @ WkvT^T + bkv
  k_tr_f32_bf16<<<dim3(32, 96), tb, 0, stream>>>(Wk, WkvT, DIM, KDIM);
  k_tr_f32_bf16<<<dim3(32, 96), tb, 0, stream>>>(Wv, WkvT + (size_t)1024 * DIM, DIM, KDIM);
  k_bkv<<<8, 256, 0, stream>>>(bk, bv, bkv);
  k_gemm_bt<true, true><<<dim3(256, 1), 256, 0, stream>>>(hs_bf, WkvT, kv_bf, bkv,
      2048, 2048, DIM, DIM, DIM, 2048, 0, 0, 0, 0, 0, 0);
  // gram for all 4 slices (k/v x batch): zb = b*2 + kv
  k_gemm_bt<false, false><<<dim3(64, 4), 256, 0, stream>>>(kv_bf, kv_bf, gram4, nullptr,
      SEQ, SEQ, KDIM, 2048, 2048, SEQ,
      KVB, 1024, KVB, 1024, 2 * SS, SS);
  k_norms<<<4, 1024, 0, stream>>>(gram4, nrm4, anyCnt);
  k_rowany<<<dim3(SEQ, 4), 256, 0, stream>>>(gram4, nrm4, rowAny4, anyCnt);
  k_scan_replace<<<4, 1024, 0, stream>>>(gram4, nrm4, rowAny4, anyCnt, kv_bf);
  // KKT = K_new @ [Wqk;bqk;0]^T per batch
  k_build_wqke<<<128, 256, 0, stream>>>(Wqk, bqk, WqkE);
  k_gemm_bt<true, false><<<dim3(8, 2), 256, 0, stream>>>(kv_bf, WqkE, KKTe, nullptr,
      SEQ, 128, KDIM, 2048, KDIM, 128, 0, KVB, 0, 0, 0, (long long)SEQ * 128);
  // V^T per batch ; Wo^T
  k_tr_bf16<<<dim3(32, 32, 2), tb, 0, stream>>>(kv_bf + 1024, vTb, 2048, SEQ, KVB, SS);
  k_tr_f32_bf16<<<dim3(96, 32), tb, 0, stream>>>(Wo, WoT, KDIM, DIM);
  // attention probabilities + head-mean partials (no atomics)
  k_attn3<<<512, 1024, 0, stream>>>(q_bf, KKTe, pbarP);
  k_reduce_pbar<<<1024, 256, 0, stream>>>(pbarP, Pbar_bf);
  // pv = Pbar @ V per batch
  k_gemm_bt<true, false><<<dim3(64, 2), 256, 0, stream>>>(Pbar_bf, vTb, pv_out, nullptr,
      SEQ, KDIM, SEQ, SEQ, SEQ, KDIM, 0, SS, 0, SS, 0, SS);
  // out = pv @ Wo + bo
  k_gemm_bt<false, true><<<dim3(384, 1), 256, 0, stream>>>(pv_out, WoT, (float*)d_out, bo,
      2048, DIM, KDIM, KDIM, KDIM, DIM, 0, 0, 0, 0, 0, 0);
}

// Round 5
// 309.975 us; speedup vs baseline: 6.8641x; 1.0825x over previous
//
#include <hip/hip_runtime.h>
#include <hip/hip_bf16.h>
#include <stdint.h>

#define BATCH 2
#define SEQ   1024
#define DIM   3072
#define KDIM  1024
#define NHEAD 32
#define HDQ   96
#define THR_SIM 0.95f

typedef unsigned short u16;
typedef __attribute__((ext_vector_type(8))) short short8;
typedef __attribute__((ext_vector_type(4))) float f32x4;

typedef const __attribute__((address_space(1))) unsigned int* gas_ptr;
typedef __attribute__((address_space(3))) unsigned int* las_ptr;

__device__ __forceinline__ void glds16(const u16* g, u16* l) {
  __builtin_amdgcn_global_load_lds((gas_ptr)g, (las_ptr)l, 16, 0, 0);
}

__device__ __forceinline__ u16 f2bf(float f) {
  union { float f; unsigned u; } v; v.f = f;
  unsigned r = v.u + 0x7FFFu + ((v.u >> 16) & 1u);
  return (u16)(r >> 16);
}
__device__ __forceinline__ float bf2f(u16 x) {
  union { unsigned u; float f; } v; v.u = ((unsigned)x) << 16; return v.f;
}

__device__ __forceinline__ f32x4 mfma16(short8 a, short8 b, f32x4 c) {
  return __builtin_amdgcn_mfma_f32_16x16x32_bf16(a, b, c, 0, 0, 0);
}

// ---------------- fp32 -> bf16 convert (vectorized) ----------------
__global__ void k_cvt_bf16(const float* __restrict__ in, u16* __restrict__ out, int n4) {
  int i = blockIdx.x * blockDim.x + threadIdx.x;
  if (i < n4) {
    float4 v = ((const float4*)in)[i];
    ushort4 o;
    o.x = f2bf(v.x); o.y = f2bf(v.y); o.z = f2bf(v.z); o.w = f2bf(v.w);
    ((ushort4*)out)[i] = o;
  }
}

// ---------------- transpose fp32 (R,C) -> bf16 (C,R) ----------------
__global__ void k_tr_f32_bf16(const float* __restrict__ in, u16* __restrict__ out, int R, int C) {
  __shared__ float t[32][33];
  int c0 = blockIdx.x * 32, r0 = blockIdx.y * 32;
  int tx = threadIdx.x, ty = threadIdx.y; // (32,8)
  #pragma unroll
  for (int k = 0; k < 4; ++k)
    t[ty + 8 * k][tx] = in[(size_t)(r0 + ty + 8 * k) * C + c0 + tx];
  __syncthreads();
  #pragma unroll
  for (int k = 0; k < 4; ++k)
    out[(size_t)(c0 + ty + 8 * k) * R + r0 + tx] = f2bf(t[tx][ty + 8 * k]);
}

// ---------------- transpose bf16 (R,C) -> (C,R), strided, batched over z ----------------
__global__ void k_tr_bf16(const u16* __restrict__ in, u16* __restrict__ out,
                          int ldin, int ldout, long long zsIn, long long zsOut) {
  __shared__ u16 t[32][33];
  const u16* ib = in + (size_t)blockIdx.z * zsIn;
  u16* ob = out + (size_t)blockIdx.z * zsOut;
  int c0 = blockIdx.x * 32, r0 = blockIdx.y * 32;
  int tx = threadIdx.x, ty = threadIdx.y;
  #pragma unroll
  for (int k = 0; k < 4; ++k)
    t[ty + 8 * k][tx] = ib[(size_t)(r0 + ty + 8 * k) * ldin + c0 + tx];
  __syncthreads();
  #pragma unroll
  for (int k = 0; k < 4; ++k)
    ob[(size_t)(c0 + ty + 8 * k) * ldout + r0 + tx] = t[tx][ty + 8 * k];
}

// ---------------- build extended Wqk operand: rows 0..95 = Wqk, row 96 = bqk, 97..127 = 0 ----------------
__global__ void k_build_wqke(const float* __restrict__ Wqk, const float* __restrict__ bqk,
                             u16* __restrict__ out) {
  const int n = blockIdx.x;           // 0..127
  const int c = threadIdx.x * 4;      // 256 threads x 4
  float4 v;
  if (n < 96)       v = *(const float4*)(Wqk + (size_t)n * KDIM + c);
  else if (n == 96) v = *(const float4*)(bqk + c);
  else              v = make_float4(0.f, 0.f, 0.f, 0.f);
  ushort4 o;
  o.x = f2bf(v.x); o.y = f2bf(v.y); o.z = f2bf(v.z); o.w = f2bf(v.w);
  *(ushort4*)(out + (size_t)n * KDIM + c) = o;
}

// ---------------- concat bk|bv ----------------
__global__ void k_bkv(const float* __restrict__ bk, const float* __restrict__ bv,
                      float* __restrict__ out) {
  int i = blockIdx.x * 256 + threadIdx.x;
  if (i < 2048) out[i] = (i < 1024) ? bk[i] : bv[i - 1024];
}

// ---------------- GEMM: C = A(M,K;lda) @ Bt(N,K;ldb)^T (+bias[N]) ----------------
// 128x64 tile, BK=32, 4 waves (2x2, wave-tile 64x32), glds dbuf staging.
// LDS bank-conflict fix: source col-block XOR swizzle sc ^= (srow>>1)&3 (pre-swizzled
// global address, linear LDS dest per glds constraint), same XOR on ds_read.
// batch offsets: off = (zb>>1)*bsH + (zb&1)*bsL for A, B, C.
template<bool OUT_BF16, bool BIAS>
__global__ __launch_bounds__(256, 4) void k_gemm_bt(
    const u16* __restrict__ A, const u16* __restrict__ Bt, void* __restrict__ Cv,
    const float* __restrict__ bias, int M, int N, int K,
    int lda, int ldb, int ldc,
    long long bsAH, long long bsAL, long long bsBH, long long bsBL,
    long long bsCH, long long bsCL)
{
  const int zb = blockIdx.y, zH = zb >> 1, zL = zb & 1;
  A  += (size_t)(zH * bsAH + zL * bsAL);
  Bt += (size_t)(zH * bsBH + zL * bsBL);
  u16*   Cb16 = (u16*)Cv + (size_t)(zH * bsCH + zL * bsCL);
  float* Cf32 = (float*)Cv + (size_t)(zH * bsCH + zL * bsCL);

  __shared__ u16 As[2][128 * 32];
  __shared__ u16 Bs[2][64 * 32];
  const int nt = N >> 6;
  const int tm = blockIdx.x / nt, tn = blockIdx.x % nt;
  const int tid = threadIdx.x, lane = tid & 63, wid = tid >> 6;
  const int wr = wid >> 1, wc = wid & 1, li = lane & 15, lg = lane >> 4;

  const int srow = tid >> 2;                         // 0..63
  const int scol = (((tid & 3) ^ ((srow >> 1) & 3)) << 3);  // swizzled col block
  const u16* gA0 = A + (size_t)(tm * 128 + srow) * lda + scol;
  const u16* gA1 = gA0 + (size_t)64 * lda;
  const u16* gB0 = Bt + (size_t)(tn * 64 + srow) * ldb + scol;
  const int wof = wid * 512;   // wave-uniform LDS chunk (64 lanes x 8 elems)

  f32x4 acc[4][2];
  #pragma unroll
  for (int a = 0; a < 4; ++a)
    #pragma unroll
    for (int b = 0; b < 2; ++b) acc[a][b] = (f32x4){0.f, 0.f, 0.f, 0.f};

  const int sl = (lg ^ ((li >> 1) & 3)) * 8;         // swizzled ds_read col offset

  const int nk = K >> 5;
  glds16(gA0, As[0] + wof);
  glds16(gA1, As[0] + 2048 + wof);
  glds16(gB0, Bs[0] + wof);
  __syncthreads();

  int cur = 0;
  for (int kt = 0; kt < nk; ++kt) {
    if (kt + 1 < nk) {
      const int k0 = (kt + 1) << 5;
      glds16(gA0 + k0, As[cur ^ 1] + wof);
      glds16(gA1 + k0, As[cur ^ 1] + 2048 + wof);
      glds16(gB0 + k0, Bs[cur ^ 1] + wof);
    }
    short8 af[4], bfv[2];
    #pragma unroll
    for (int mf = 0; mf < 4; ++mf)
      af[mf] = *(const short8*)(As[cur] + (wr * 64 + mf * 16 + li) * 32 + sl);
    #pragma unroll
    for (int nf = 0; nf < 2; ++nf)
      bfv[nf] = *(const short8*)(Bs[cur] + (wc * 32 + nf * 16 + li) * 32 + sl);
    #pragma unroll
    for (int mf = 0; mf < 4; ++mf)
      #pragma unroll
      for (int nf = 0; nf < 2; ++nf)
        acc[mf][nf] = mfma16(af[mf], bfv[nf], acc[mf][nf]);
    __syncthreads();
    cur ^= 1;
  }
  #pragma unroll
  for (int mf = 0; mf < 4; ++mf) {
    #pragma unroll
    for (int nf = 0; nf < 2; ++nf) {
      const int col = tn * 64 + wc * 32 + nf * 16 + li;
      const float bb = BIAS ? bias[col] : 0.f;
      #pragma unroll
      for (int j = 0; j < 4; ++j) {
        const int row = tm * 128 + wr * 64 + mf * 16 + lg * 4 + j;
        const float v = acc[mf][nf][j] + bb;
        if (OUT_BF16) Cb16[(size_t)row * ldc + col] = f2bf(v);
        else          Cf32[(size_t)row * ldc + col] = v;
      }
    }
  }
}

// ---------------- token replacement: norms, rowAny (parallel), scan+gather ----------------
// 4 slices: s = b*2 + kv; gram slice s at gram + s*SEQ*SEQ; data row view in kv_bf.
__global__ void k_norms(const float* __restrict__ gram, float* __restrict__ nrm,
                        int* __restrict__ anyCnt) {
  const int s = blockIdx.x, j = threadIdx.x;
  const float* g = gram + (size_t)s * SEQ * SEQ;
  float nj = fmaxf(sqrtf(fmaxf(g[(size_t)j * SEQ + j], 0.f)), 1e-8f);
  nrm[s * SEQ + j] = nj;
  if (j == 0) anyCnt[s] = 0;
}

__global__ void k_rowany(const float* __restrict__ gram, const float* __restrict__ nrm,
                         unsigned char* __restrict__ rowAny, int* __restrict__ anyCnt) {
  const int i = blockIdx.x, s = blockIdx.y, t = threadIdx.x; // 256 threads
  const float* g = gram + (size_t)s * SEQ * SEQ + (size_t)i * SEQ;
  const float* nr = nrm + s * SEQ;
  const float ni = nr[i];
  int any = 0;
  for (int j = i + 1 + t; j < SEQ; j += 256)
    any |= (g[j] > THR_SIM * ni * nr[j]) ? 1 : 0;
  any = __any(any) ? 1 : 0;
  __shared__ int sh[4];
  if ((t & 63) == 0) sh[t >> 6] = any;
  __syncthreads();
  if (t == 0) {
    int a = sh[0] | sh[1] | sh[2] | sh[3];
    rowAny[s * SEQ + i] = (unsigned char)a;
    if (a) atomicAdd(&anyCnt[s], 1);
  }
}

__global__ __launch_bounds__(1024) void k_scan_replace(
    const float* __restrict__ gram, const float* __restrict__ nrmG,
    const unsigned char* __restrict__ rowAnyG, const int* __restrict__ anyCnt,
    u16* __restrict__ kvbase)
{
  const int s = blockIdx.x;
  if (anyCnt[s] == 0) return;  // block-uniform fast path
  const float* g = gram + (size_t)s * SEQ * SEQ;
  u16* dat = kvbase + (size_t)(s >> 1) * (2048 * 2048 / 2) * 2 + (size_t)(s & 1) * 1024;
  const int ldr = 2048;
  __shared__ float nrm[SEQ];
  __shared__ unsigned char used[SEQ];
  __shared__ unsigned char rowAny[SEQ];
  __shared__ short rep[SEQ];
  const int j = threadIdx.x;
  nrm[j] = nrmG[s * SEQ + j];
  rowAny[j] = rowAnyG[s * SEQ + j];
  used[j] = 0; rep[j] = (short)j;
  __syncthreads();
  for (int i = 0; i < SEQ - 1; ++i) {
    if (rowAny[i] && !used[i]) {
      const float t = THR_SIM * nrm[i];
      if (j > i && !used[j] && g[(size_t)i * SEQ + j] > t * nrm[j]) {
        used[j] = 1; rep[j] = (short)i;
      }
      __syncthreads();
    }
  }
  __syncthreads();
  const int src = rep[j];
  if (src != j) {
    for (int c = 0; c < KDIM; c += 8)
      *(uint4*)(dat + (size_t)j * ldr + c) = *(const uint4*)(dat + (size_t)src * ldr + c);
  }
}

// ---------------- attention probabilities + head-mean partials ----------------
// Swapped-operand MFMA: A = KKT keys (cached in regs across heads), B = q rows.
// grid 512 = xcd(8: b x pg) x 64 q-tiles of 16 rows. 1024 threads = 16 waves,
// wave w owns keys [w*64, w*64+64). One barrier per head (flash combine, 2 LDS slots).
__global__ __launch_bounds__(1024, 4) void k_attn3(
    const u16* __restrict__ q_bf, const u16* __restrict__ KKTe,
    u16* __restrict__ pbarP)
{
  const int bid = blockIdx.x;
  const int xcd = bid & 7, qt = bid >> 3;
  const int b = xcd >> 2, pg = xcd & 3;
  const int q0 = qt * 16;
  const int tid = threadIdx.x, lane = tid & 63, w = tid >> 6;
  const int li = lane & 15, lg = lane >> 4;

  __shared__ float bkkl[1024];
  __shared__ float2 red[2][16][16];

  const u16* KKb = KKTe + (size_t)b * SEQ * 128;
  bkkl[tid] = bf2f(KKb[(size_t)tid * 128 + 96]);

  short8 ak[4][3];
  #pragma unroll
  for (int kf = 0; kf < 4; ++kf)
    #pragma unroll
    for (int ks = 0; ks < 3; ++ks)
      ak[kf][ks] = *(const short8*)(KKb + (size_t)(w * 64 + kf * 16 + li) * 128 + ks * 32 + lg * 8);

  f32x4 accm[4];
  #pragma unroll
  for (int kf = 0; kf < 4; ++kf) accm[kf] = (f32x4){0.f, 0.f, 0.f, 0.f};
  __syncthreads();

  const u16* qrow = q_bf + (size_t)(b * SEQ + q0 + li) * DIM + pg * 8 * HDQ;

  for (int hh = 0; hh < 8; ++hh) {
    const u16* qp = qrow + hh * HDQ;
    f32x4 acc[4];
    #pragma unroll
    for (int kf = 0; kf < 4; ++kf) acc[kf] = (f32x4){0.f, 0.f, 0.f, 0.f};
    #pragma unroll
    for (int ks = 0; ks < 3; ++ks) {
      short8 bq = *(const short8*)(qp + ks * 32 + lg * 8);
      #pragma unroll
      for (int kf = 0; kf < 4; ++kf)
        acc[kf] = mfma16(ak[kf][ks], bq, acc[kf]);
    }
    // bias + scale, local max over this wave's 64 keys for q-row li
    float m = -1e30f;
    #pragma unroll
    for (int kf = 0; kf < 4; ++kf) {
      f32x4 bb = *(const f32x4*)(bkkl + w * 64 + kf * 16 + lg * 4);
      #pragma unroll
      for (int j = 0; j < 4; ++j) {
        float s = (acc[kf][j] + bb[j]) * 0.03125f;
        acc[kf][j] = s;
        m = fmaxf(m, s);
      }
    }
    m = fmaxf(m, __shfl_xor(m, 16));
    m = fmaxf(m, __shfl_xor(m, 32));
    float ssum = 0.f;
    #pragma unroll
    for (int kf = 0; kf < 4; ++kf)
      #pragma unroll
      for (int j = 0; j < 4; ++j) {
        float pv = __expf(acc[kf][j] - m);
        acc[kf][j] = pv;
        ssum += pv;
      }
    ssum += __shfl_xor(ssum, 16);
    ssum += __shfl_xor(ssum, 32);
    if (lane < 16) red[hh & 1][w][li] = make_float2(m, ssum);
    __syncthreads();
    // combine 16 wave-partials (flash rescale)
    float mg = -1e30f;
    #pragma unroll
    for (int ww = 0; ww < 16; ++ww) mg = fmaxf(mg, red[hh & 1][ww][li].x);
    float Sg = 0.f;
    #pragma unroll
    for (int ww = 0; ww < 16; ++ww) {
      float2 msv = red[hh & 1][ww][li];
      Sg += msv.y * __expf(msv.x - mg);
    }
    const float gi = __expf(m - mg) / (32.f * Sg);
    #pragma unroll
    for (int kf = 0; kf < 4; ++kf)
      #pragma unroll
      for (int j = 0; j < 4; ++j)
        accm[kf][j] += acc[kf][j] * gi;
  }

  u16* dst = pbarP + (size_t)(pg * 2 + b) * SEQ * SEQ + (size_t)(q0 + li) * SEQ + w * 64;
  #pragma unroll
  for (int kf = 0; kf < 4; ++kf) {
    ushort4 o;
    o.x = f2bf(accm[kf][0]); o.y = f2bf(accm[kf][1]);
    o.z = f2bf(accm[kf][2]); o.w = f2bf(accm[kf][3]);
    *(ushort4*)(dst + kf * 16 + lg * 4) = o;
  }
}

// ---------------- reduce 4 Pbar partials -> bf16 Pbar ----------------
__global__ void k_reduce_pbar(const u16* __restrict__ part, u16* __restrict__ out) {
  const size_t N = (size_t)BATCH * SEQ * SEQ;
  size_t i = (size_t)blockIdx.x * blockDim.x + threadIdx.x; // 8-elem chunk
  if (i >= N / 8) return;
  short8 p0 = ((const short8*)part)[i];
  short8 p1 = ((const short8*)(part + N))[i];
  short8 p2 = ((const short8*)(part + 2 * N))[i];
  short8 p3 = ((const short8*)(part + 3 * N))[i];
  short8 o;
  #pragma unroll
  for (int j = 0; j < 8; ++j) {
    float s = bf2f((u16)p0[j]) + bf2f((u16)p1[j]) + bf2f((u16)p2[j]) + bf2f((u16)p3[j]);
    o[j] = (short)f2bf(s);
  }
  ((short8*)out)[i] = o;
}

// ---------------- host ----------------
extern "C" void kernel_launch(void* const* d_in, const int* in_sizes, int n_in,
                              void* d_out, int out_size, void* d_ws, size_t ws_size,
                              hipStream_t stream)
{
  (void)in_sizes; (void)n_in; (void)out_size;
  const float* hs  = (const float*)d_in[0];
  const float* Wq  = (const float*)d_in[1];
  const float* bq  = (const float*)d_in[2];
  const float* Wk  = (const float*)d_in[3];
  const float* bk  = (const float*)d_in[4];
  const float* Wv  = (const float*)d_in[5];
  const float* bv  = (const float*)d_in[6];
  const float* Wqk = (const float*)d_in[7];
  const float* bqk = (const float*)d_in[8];
  const float* Wo  = (const float*)d_in[9];
  const float* bo  = (const float*)d_in[10];

  // workspace layout (sequential lifetimes):
  // [0,12.58M) hs_bf -> gram4 [0,16.78M) (after kv GEMM) -> pbarP [0,16.78M) (after scans)
  // [12.58M,31.46M) WqT -> WkvT [12.58M,25.17M) -> {WqkE,KKTe,vTb,WoT} after kv GEMM
  // [31.46M,44.04M) q_bf ; [44.04M,52.43M) kv_bf -> {Pbar_bf,pv_out}
  // [52.43M,..) smalls
  char* p = (char*)d_ws;
  u16*   hs_bf   = (u16*)(p + 0);
  float* gram4   = (float*)(p + 0);                // 16,777,216 B
  u16*   pbarP   = (u16*)(p + 0);                  // 16,777,216 B
  u16*   WqT     = (u16*)(p + 12582912);           // 18,874,368 B
  u16*   WkvT    = (u16*)(p + 12582912);           // 12,582,912 B
  u16*   WqkE    = (u16*)(p + 16777216);           //    262,144 B
  u16*   KKTe    = (u16*)(p + 17039360);           //    524,288 B
  u16*   vTb     = (u16*)(p + 17563648);           //  4,194,304 B
  u16*   WoT     = (u16*)(p + 21757952);           //  6,291,456 B
  u16*   q_bf    = (u16*)(p + 31457280);           // 12,582,912 B
  u16*   kv_bf   = (u16*)(p + 44040192);           //  8,388,608 B
  u16*   Pbar_bf = (u16*)(p + 44040192);           //  4,194,304 B (after kv dead)
  u16*   pv_out  = (u16*)(p + 48234496);           //  4,194,304 B
  float* bkv     = (float*)(p + 52428800);         //      8,192 B
  float* nrm4    = (float*)(p + 52436992);         //     16,384 B
  unsigned char* rowAny4 = (unsigned char*)(p + 52453376); // 4,096 B
  int*   anyCnt  = (int*)(p + 52457472);           //         16 B
  if (ws_size < 58916864) return;

  const dim3 tb(32, 8);
  const long long SS = (long long)SEQ * SEQ;       // 1,048,576
  const long long KVB = 2048LL * 1024;             // kv batch stride (elems) = 2,097,152

  // hs -> bf16 ; Wq^T ; q = hs @ Wq^T + bq  (grid 16x48 = 768 blocks, 3/CU)
  k_cvt_bf16<<<6144, 256, 0, stream>>>(hs, hs_bf, BATCH * SEQ * DIM / 4);
  k_tr_f32_bf16<<<dim3(96, 96), tb, 0, stream>>>(Wq, WqT, DIM, DIM);
  k_gemm_bt<true, true><<<dim3(768, 1), 256, 0, stream>>>(hs_bf, WqT, q_bf, bq,
      2048, DIM, DIM, DIM, DIM, DIM, 0, 0, 0, 0, 0, 0);
  // WkvT = [Wk^T ; Wv^T] ; bkv ; kv = hs @ WkvT^T + bkv  (grid 16x32 = 512)
  k_tr_f32_bf16<<<dim3(32, 96), tb, 0, stream>>>(Wk, WkvT, DIM, KDIM);
  k_tr_f32_bf16<<<dim3(32, 96), tb, 0, stream>>>(Wv, WkvT + (size_t)1024 * DIM, DIM, KDIM);
  k_bkv<<<8, 256, 0, stream>>>(bk, bv, bkv);
  k_gemm_bt<true, true><<<dim3(512, 1), 256, 0, stream>>>(hs_bf, WkvT, kv_bf, bkv,
      2048, 2048, DIM, DIM, DIM, 2048, 0, 0, 0, 0, 0, 0);
  // gram for all 4 slices (k/v x batch): zb = b*2 + kv  (grid 128x4 = 512)
  k_gemm_bt<false, false><<<dim3(128, 4), 256, 0, stream>>>(kv_bf, kv_bf, gram4, nullptr,
      SEQ, SEQ, KDIM, 2048, 2048, SEQ,
      KVB, 1024, KVB, 1024, 2 * SS, SS);
  k_norms<<<4, 1024, 0, stream>>>(gram4, nrm4, anyCnt);
  k_rowany<<<dim3(SEQ, 4), 256, 0, stream>>>(gram4, nrm4, rowAny4, anyCnt);
  k_scan_replace<<<4, 1024, 0, stream>>>(gram4, nrm4, rowAny4, anyCnt, kv_bf);
  // KKT = K_new @ [Wqk;bqk;0]^T per batch  (grid 16x2)
  k_build_wqke<<<128, 256, 0, stream>>>(Wqk, bqk, WqkE);
  k_gemm_bt<true, false><<<dim3(16, 2), 256, 0, stream>>>(kv_bf, WqkE, KKTe, nullptr,
      SEQ, 128, KDIM, 2048, KDIM, 128, 0, KVB, 0, 0, 0, (long long)SEQ * 128);
  // V^T per batch ; Wo^T
  k_tr_bf16<<<dim3(32, 32, 2), tb, 0, stream>>>(kv_bf + 1024, vTb, 2048, SEQ, KVB, SS);
  k_tr_f32_bf16<<<dim3(96, 32), tb, 0, stream>>>(Wo, WoT, KDIM, DIM);
  // attention probabilities + head-mean partials (no atomics)
  k_attn3<<<512, 1024, 0, stream>>>(q_bf, KKTe, pbarP);
  k_reduce_pbar<<<1024, 256, 0, stream>>>(pbarP, Pbar_bf);
  // pv = Pbar @ V per batch  (grid 128x2 = 256)
  k_gemm_bt<true, false><<<dim3(128, 2), 256, 0, stream>>>(Pbar_bf, vTb, pv_out, nullptr,
      SEQ, KDIM, SEQ, SEQ, SEQ, KDIM, 0, SS, 0, SS, 0, SS);
  // out = pv @ Wo + bo  (grid 16x48 = 768)
  k_gemm_bt<false, true><<<dim3(768, 1), 256, 0, stream>>>(pv_out, WoT, (float*)d_out, bo,
      2048, DIM, KDIM, KDIM, KDIM, DIM, 0, 0, 0, 0, 0, 0);
}

// Round 6
// 251.029 us; speedup vs baseline: 8.4759x; 1.2348x over previous
//
#include <hip/hip_runtime.h>
#include <hip/hip_bf16.h>
#include <stdint.h>

#define BATCH 2
#define SEQ   1024
#define DIM   3072
#define KDIM  1024
#define NHEAD 32
#define HDQ   96
#define THR_SIM 0.95f

typedef unsigned short u16;
typedef __attribute__((ext_vector_type(8))) short short8;
typedef __attribute__((ext_vector_type(4))) float f32x4;

typedef const __attribute__((address_space(1))) unsigned int* gas_ptr;
typedef __attribute__((address_space(3))) unsigned int* las_ptr;

__device__ __forceinline__ void glds16(const u16* g, u16* l) {
  __builtin_amdgcn_global_load_lds((gas_ptr)g, (las_ptr)l, 16, 0, 0);
}

__device__ __forceinline__ u16 f2bf(float f) {
  union { float f; unsigned u; } v; v.f = f;
  unsigned r = v.u + 0x7FFFu + ((v.u >> 16) & 1u);
  return (u16)(r >> 16);
}
__device__ __forceinline__ float bf2f(u16 x) {
  union { unsigned u; float f; } v; v.u = ((unsigned)x) << 16; return v.f;
}

__device__ __forceinline__ f32x4 mfma16(short8 a, short8 b, f32x4 c) {
  return __builtin_amdgcn_mfma_f32_16x16x32_bf16(a, b, c, 0, 0, 0);
}

// ---------------- fp32 -> bf16 convert (vectorized) ----------------
__global__ void k_cvt_bf16(const float* __restrict__ in, u16* __restrict__ out, int n4) {
  int i = blockIdx.x * blockDim.x + threadIdx.x;
  if (i < n4) {
    float4 v = ((const float4*)in)[i];
    ushort4 o;
    o.x = f2bf(v.x); o.y = f2bf(v.y); o.z = f2bf(v.z); o.w = f2bf(v.w);
    ((ushort4*)out)[i] = o;
  }
}

// ---------------- transpose fp32 (R,C) -> bf16 (C,R) ----------------
__global__ void k_tr_f32_bf16(const float* __restrict__ in, u16* __restrict__ out, int R, int C) {
  __shared__ float t[32][33];
  int c0 = blockIdx.x * 32, r0 = blockIdx.y * 32;
  int tx = threadIdx.x, ty = threadIdx.y; // (32,8)
  #pragma unroll
  for (int k = 0; k < 4; ++k)
    t[ty + 8 * k][tx] = in[(size_t)(r0 + ty + 8 * k) * C + c0 + tx];
  __syncthreads();
  #pragma unroll
  for (int k = 0; k < 4; ++k)
    out[(size_t)(c0 + ty + 8 * k) * R + r0 + tx] = f2bf(t[tx][ty + 8 * k]);
}

// ---------------- transpose bf16 (R,C) -> (C,R), strided, batched over z ----------------
__global__ void k_tr_bf16(const u16* __restrict__ in, u16* __restrict__ out,
                          int ldin, int ldout, long long zsIn, long long zsOut) {
  __shared__ u16 t[32][33];
  const u16* ib = in + (size_t)blockIdx.z * zsIn;
  u16* ob = out + (size_t)blockIdx.z * zsOut;
  int c0 = blockIdx.x * 32, r0 = blockIdx.y * 32;
  int tx = threadIdx.x, ty = threadIdx.y;
  #pragma unroll
  for (int k = 0; k < 4; ++k)
    t[ty + 8 * k][tx] = ib[(size_t)(r0 + ty + 8 * k) * ldin + c0 + tx];
  __syncthreads();
  #pragma unroll
  for (int k = 0; k < 4; ++k)
    ob[(size_t)(c0 + ty + 8 * k) * ldout + r0 + tx] = t[tx][ty + 8 * k];
}

// ---------------- build extended Wqk operand: rows 0..95 = Wqk, row 96 = bqk, 97..127 = 0 ----------------
__global__ void k_build_wqke(const float* __restrict__ Wqk, const float* __restrict__ bqk,
                             u16* __restrict__ out) {
  const int n = blockIdx.x;           // 0..127
  const int c = threadIdx.x * 4;      // 256 threads x 4
  float4 v;
  if (n < 96)       v = *(const float4*)(Wqk + (size_t)n * KDIM + c);
  else if (n == 96) v = *(const float4*)(bqk + c);
  else              v = make_float4(0.f, 0.f, 0.f, 0.f);
  ushort4 o;
  o.x = f2bf(v.x); o.y = f2bf(v.y); o.z = f2bf(v.z); o.w = f2bf(v.w);
  *(ushort4*)(out + (size_t)n * KDIM + c) = o;
}

// ---------------- concat bk|bv ----------------
__global__ void k_bkv(const float* __restrict__ bk, const float* __restrict__ bv,
                      float* __restrict__ out) {
  int i = blockIdx.x * 256 + threadIdx.x;
  if (i < 2048) out[i] = (i < 1024) ? bk[i] : bv[i - 1024];
}

// ---------------- GEMM: C = A(M,K;lda) @ Bt(N,K;ldb)^T (+bias[N]) ----------------
// 128x64 tile, BK=64, 4 waves (2x2, wave-tile 64x32), glds dbuf staging,
// XCD-bijective block swizzle (contiguous tm-major chunk per XCD -> A-panels L2-hot).
// LDS swizzle for 128B row stride: source colblk ^= (lane>>3); read colblk ^= (li&7).
// batch offsets: off = (zb>>1)*bsH + (zb&1)*bsL for A, B, C.
template<bool OUT_BF16, bool BIAS>
__global__ __launch_bounds__(256, 3) void k_gemm_bt(
    const u16* __restrict__ A, const u16* __restrict__ Bt, void* __restrict__ Cv,
    const float* __restrict__ bias, int M, int N, int K,
    int lda, int ldb, int ldc,
    long long bsAH, long long bsAL, long long bsBH, long long bsBL,
    long long bsCH, long long bsCL)
{
  const int zb = blockIdx.y, zH = zb >> 1, zL = zb & 1;
  A  += (size_t)(zH * bsAH + zL * bsAL);
  Bt += (size_t)(zH * bsBH + zL * bsBL);
  u16*   Cb16 = (u16*)Cv + (size_t)(zH * bsCH + zL * bsCL);
  float* Cf32 = (float*)Cv + (size_t)(zH * bsCH + zL * bsCL);

  __shared__ u16 Ls[2][24 * 512];   // per buf: A 16KB (chunks 0-15) + B 8KB (chunks 16-23)
  const int nt = N >> 6;
  // XCD-bijective swizzle (m204): XCD x = bid&7 gets a contiguous logical range
  int bid = blockIdx.x;
  {
    const int nwg = gridDim.x;
    const int qq = nwg >> 3, rr = nwg & 7;
    const int x = bid & 7, pos = bid >> 3;
    bid = (x < rr ? x * (qq + 1) : rr * (qq + 1) + (x - rr) * qq) + pos;
  }
  const int tm = bid / nt, tn = bid % nt;
  const int tid = threadIdx.x, lane = tid & 63, wid = tid >> 6;
  const int wr = wid >> 1, wc = wid & 1, li = lane & 15, lg = lane >> 4;

  // staging: 24 chunks of 1KB (8 rows x 64 cols bf16); wave w owns chunks w*6..w*6+5.
  // lane l covers row (l>>3), colblk (l&7) of the chunk; source colblk pre-swizzled.
  const int rsub = lane >> 3;
  const int cbe = ((lane & 7) ^ rsub) << 3;   // swizzled source col offset (elems)
  const u16* gp[6];
  int lof[6];
  #pragma unroll
  for (int j = 0; j < 6; ++j) {
    const int ci = wid * 6 + j;
    lof[j] = ci << 9;
    if (ci < 16) gp[j] = A + (size_t)(tm * 128 + ci * 8 + rsub) * lda + cbe;
    else         gp[j] = Bt + (size_t)(tn * 64 + (ci - 16) * 8 + rsub) * ldb + cbe;
  }

  f32x4 acc[4][2];
  #pragma unroll
  for (int a = 0; a < 4; ++a)
    #pragma unroll
    for (int b = 0; b < 2; ++b) acc[a][b] = (f32x4){0.f, 0.f, 0.f, 0.f};

  const int nk = K >> 6;
  #pragma unroll
  for (int j = 0; j < 6; ++j) { glds16(gp[j], Ls[0] + lof[j]); gp[j] += 64; }
  __syncthreads();

  for (int kt = 0; kt < nk; ++kt) {
    const u16* Lc = Ls[kt & 1];
    if (kt + 1 < nk) {
      u16* Ln = Ls[(kt + 1) & 1];
      #pragma unroll
      for (int j = 0; j < 6; ++j) { glds16(gp[j], Ln + lof[j]); gp[j] += 64; }
    }
    short8 af[2][4], bfv[2][2];
    #pragma unroll
    for (int ks = 0; ks < 2; ++ks) {
      const int sw = (((ks * 4 + lg) ^ (li & 7)) << 3);
      #pragma unroll
      for (int mf = 0; mf < 4; ++mf)
        af[ks][mf] = *(const short8*)(Lc + (wr * 64 + mf * 16 + li) * 64 + sw);
      #pragma unroll
      for (int nf = 0; nf < 2; ++nf)
        bfv[ks][nf] = *(const short8*)(Lc + 8192 + (wc * 32 + nf * 16 + li) * 64 + sw);
    }
    #pragma unroll
    for (int ks = 0; ks < 2; ++ks)
      #pragma unroll
      for (int mf = 0; mf < 4; ++mf)
        #pragma unroll
        for (int nf = 0; nf < 2; ++nf)
          acc[mf][nf] = mfma16(af[ks][mf], bfv[ks][nf], acc[mf][nf]);
    __syncthreads();
  }
  #pragma unroll
  for (int mf = 0; mf < 4; ++mf) {
    #pragma unroll
    for (int nf = 0; nf < 2; ++nf) {
      const int col = tn * 64 + wc * 32 + nf * 16 + li;
      const float bb = BIAS ? bias[col] : 0.f;
      #pragma unroll
      for (int j = 0; j < 4; ++j) {
        const int row = tm * 128 + wr * 64 + mf * 16 + lg * 4 + j;
        const float v = acc[mf][nf][j] + bb;
        if (OUT_BF16) Cb16[(size_t)row * ldc + col] = f2bf(v);
        else          Cf32[(size_t)row * ldc + col] = v;
      }
    }
  }
}

// ---------------- token replacement: norms, rowAny (parallel), scan+gather ----------------
// 4 slices: s = b*2 + kv; gram slice s at gram + s*SEQ*SEQ; data row view in kv_bf.
__global__ void k_norms(const float* __restrict__ gram, float* __restrict__ nrm,
                        int* __restrict__ anyCnt) {
  const int s = blockIdx.x, j = threadIdx.x;
  const float* g = gram + (size_t)s * SEQ * SEQ;
  float nj = fmaxf(sqrtf(fmaxf(g[(size_t)j * SEQ + j], 0.f)), 1e-8f);
  nrm[s * SEQ + j] = nj;
  if (j == 0) anyCnt[s] = 0;
}

__global__ void k_rowany(const float* __restrict__ gram, const float* __restrict__ nrm,
                         unsigned char* __restrict__ rowAny, int* __restrict__ anyCnt) {
  const int i = blockIdx.x, s = blockIdx.y, t = threadIdx.x; // 256 threads
  const float* g = gram + (size_t)s * SEQ * SEQ + (size_t)i * SEQ;
  const float* nr = nrm + s * SEQ;
  const float ni = nr[i];
  int any = 0;
  for (int j = i + 1 + t; j < SEQ; j += 256)
    any |= (g[j] > THR_SIM * ni * nr[j]) ? 1 : 0;
  any = __any(any) ? 1 : 0;
  __shared__ int sh[4];
  if ((t & 63) == 0) sh[t >> 6] = any;
  __syncthreads();
  if (t == 0) {
    int a = sh[0] | sh[1] | sh[2] | sh[3];
    rowAny[s * SEQ + i] = (unsigned char)a;
    if (a) atomicAdd(&anyCnt[s], 1);
  }
}

__global__ __launch_bounds__(1024) void k_scan_replace(
    const float* __restrict__ gram, const float* __restrict__ nrmG,
    const unsigned char* __restrict__ rowAnyG, const int* __restrict__ anyCnt,
    u16* __restrict__ kvbase)
{
  const int s = blockIdx.x;
  if (anyCnt[s] == 0) return;  // block-uniform fast path
  const float* g = gram + (size_t)s * SEQ * SEQ;
  u16* dat = kvbase + (size_t)(s >> 1) * (2048 * 2048 / 2) * 2 + (size_t)(s & 1) * 1024;
  const int ldr = 2048;
  __shared__ float nrm[SEQ];
  __shared__ unsigned char used[SEQ];
  __shared__ unsigned char rowAny[SEQ];
  __shared__ short rep[SEQ];
  const int j = threadIdx.x;
  nrm[j] = nrmG[s * SEQ + j];
  rowAny[j] = rowAnyG[s * SEQ + j];
  used[j] = 0; rep[j] = (short)j;
  __syncthreads();
  for (int i = 0; i < SEQ - 1; ++i) {
    if (rowAny[i] && !used[i]) {
      const float t = THR_SIM * nrm[i];
      if (j > i && !used[j] && g[(size_t)i * SEQ + j] > t * nrm[j]) {
        used[j] = 1; rep[j] = (short)i;
      }
      __syncthreads();
    }
  }
  __syncthreads();
  const int src = rep[j];
  if (src != j) {
    for (int c = 0; c < KDIM; c += 8)
      *(uint4*)(dat + (size_t)j * ldr + c) = *(const uint4*)(dat + (size_t)src * ldr + c);
  }
}

// ---------------- attention probabilities + head-mean partials ----------------
// Swapped-operand MFMA: A = KKT keys (cached in regs across heads), B = q rows.
// grid 512 = xcd(8: b x pg) x 64 q-tiles of 16 rows. 1024 threads = 16 waves,
// wave w owns keys [w*64, w*64+64). One barrier per head (flash combine, 2 LDS slots).
__global__ __launch_bounds__(1024, 4) void k_attn3(
    const u16* __restrict__ q_bf, const u16* __restrict__ KKTe,
    u16* __restrict__ pbarP)
{
  const int bid = blockIdx.x;
  const int xcd = bid & 7, qt = bid >> 3;
  const int b = xcd >> 2, pg = xcd & 3;
  const int q0 = qt * 16;
  const int tid = threadIdx.x, lane = tid & 63, w = tid >> 6;
  const int li = lane & 15, lg = lane >> 4;

  __shared__ float bkkl[1024];
  __shared__ float2 red[2][16][16];

  const u16* KKb = KKTe + (size_t)b * SEQ * 128;
  bkkl[tid] = bf2f(KKb[(size_t)tid * 128 + 96]);

  short8 ak[4][3];
  #pragma unroll
  for (int kf = 0; kf < 4; ++kf)
    #pragma unroll
    for (int ks = 0; ks < 3; ++ks)
      ak[kf][ks] = *(const short8*)(KKb + (size_t)(w * 64 + kf * 16 + li) * 128 + ks * 32 + lg * 8);

  f32x4 accm[4];
  #pragma unroll
  for (int kf = 0; kf < 4; ++kf) accm[kf] = (f32x4){0.f, 0.f, 0.f, 0.f};
  __syncthreads();

  const u16* qrow = q_bf + (size_t)(b * SEQ + q0 + li) * DIM + pg * 8 * HDQ;

  for (int hh = 0; hh < 8; ++hh) {
    const u16* qp = qrow + hh * HDQ;
    f32x4 acc[4];
    #pragma unroll
    for (int kf = 0; kf < 4; ++kf) acc[kf] = (f32x4){0.f, 0.f, 0.f, 0.f};
    #pragma unroll
    for (int ks = 0; ks < 3; ++ks) {
      short8 bq = *(const short8*)(qp + ks * 32 + lg * 8);
      #pragma unroll
      for (int kf = 0; kf < 4; ++kf)
        acc[kf] = mfma16(ak[kf][ks], bq, acc[kf]);
    }
    // bias + scale, local max over this wave's 64 keys for q-row li
    float m = -1e30f;
    #pragma unroll
    for (int kf = 0; kf < 4; ++kf) {
      f32x4 bb = *(const f32x4*)(bkkl + w * 64 + kf * 16 + lg * 4);
      #pragma unroll
      for (int j = 0; j < 4; ++j) {
        float s = (acc[kf][j] + bb[j]) * 0.03125f;
        acc[kf][j] = s;
        m = fmaxf(m, s);
      }
    }
    m = fmaxf(m, __shfl_xor(m, 16));
    m = fmaxf(m, __shfl_xor(m, 32));
    float ssum = 0.f;
    #pragma unroll
    for (int kf = 0; kf < 4; ++kf)
      #pragma unroll
      for (int j = 0; j < 4; ++j) {
        float pv = __expf(acc[kf][j] - m);
        acc[kf][j] = pv;
        ssum += pv;
      }
    ssum += __shfl_xor(ssum, 16);
    ssum += __shfl_xor(ssum, 32);
    if (lane < 16) red[hh & 1][w][li] = make_float2(m, ssum);
    __syncthreads();
    // combine 16 wave-partials (flash rescale)
    float mg = -1e30f;
    #pragma unroll
    for (int ww = 0; ww < 16; ++ww) mg = fmaxf(mg, red[hh & 1][ww][li].x);
    float Sg = 0.f;
    #pragma unroll
    for (int ww = 0; ww < 16; ++ww) {
      float2 msv = red[hh & 1][ww][li];
      Sg += msv.y * __expf(msv.x - mg);
    }
    const float gi = __expf(m - mg) / (32.f * Sg);
    #pragma unroll
    for (int kf = 0; kf < 4; ++kf)
      #pragma unroll
      for (int j = 0; j < 4; ++j)
        accm[kf][j] += acc[kf][j] * gi;
  }

  u16* dst = pbarP + (size_t)(pg * 2 + b) * SEQ * SEQ + (size_t)(q0 + li) * SEQ + w * 64;
  #pragma unroll
  for (int kf = 0; kf < 4; ++kf) {
    ushort4 o;
    o.x = f2bf(accm[kf][0]); o.y = f2bf(accm[kf][1]);
    o.z = f2bf(accm[kf][2]); o.w = f2bf(accm[kf][3]);
    *(ushort4*)(dst + kf * 16 + lg * 4) = o;
  }
}

// ---------------- reduce 4 Pbar partials -> bf16 Pbar ----------------
__global__ void k_reduce_pbar(const u16* __restrict__ part, u16* __restrict__ out) {
  const size_t N = (size_t)BATCH * SEQ * SEQ;
  size_t i = (size_t)blockIdx.x * blockDim.x + threadIdx.x; // 8-elem chunk
  if (i >= N / 8) return;
  short8 p0 = ((const short8*)part)[i];
  short8 p1 = ((const short8*)(part + N))[i];
  short8 p2 = ((const short8*)(part + 2 * N))[i];
  short8 p3 = ((const short8*)(part + 3 * N))[i];
  short8 o;
  #pragma unroll
  for (int j = 0; j < 8; ++j) {
    float s = bf2f((u16)p0[j]) + bf2f((u16)p1[j]) + bf2f((u16)p2[j]) + bf2f((u16)p3[j]);
    o[j] = (short)f2bf(s);
  }
  ((short8*)out)[i] = o;
}

// ---------------- host ----------------
extern "C" void kernel_launch(void* const* d_in, const int* in_sizes, int n_in,
                              void* d_out, int out_size, void* d_ws, size_t ws_size,
                              hipStream_t stream)
{
  (void)in_sizes; (void)n_in; (void)out_size;
  const float* hs  = (const float*)d_in[0];
  const float* Wq  = (const float*)d_in[1];
  const float* bq  = (const float*)d_in[2];
  const float* Wk  = (const float*)d_in[3];
  const float* bk  = (const float*)d_in[4];
  const float* Wv  = (const float*)d_in[5];
  const float* bv  = (const float*)d_in[6];
  const float* Wqk = (const float*)d_in[7];
  const float* bqk = (const float*)d_in[8];
  const float* Wo  = (const float*)d_in[9];
  const float* bo  = (const float*)d_in[10];

  // workspace layout (sequential lifetimes):
  // [0,12.58M) hs_bf -> gram4 [0,16.78M) (after kv GEMM) -> pbarP [0,16.78M) (after scans)
  // [12.58M,31.46M) WqT -> WkvT [12.58M,25.17M) -> {WqkE,KKTe,vTb,WoT} after kv GEMM
  // [31.46M,44.04M) q_bf ; [44.04M,52.43M) kv_bf -> {Pbar_bf,pv_out}
  // [52.43M,..) smalls
  char* p = (char*)d_ws;
  u16*   hs_bf   = (u16*)(p + 0);
  float* gram4   = (float*)(p + 0);                // 16,777,216 B
  u16*   pbarP   = (u16*)(p + 0);                  // 16,777,216 B
  u16*   WqT     = (u16*)(p + 12582912);           // 18,874,368 B
  u16*   WkvT    = (u16*)(p + 12582912);           // 12,582,912 B
  u16*   WqkE    = (u16*)(p + 16777216);           //    262,144 B
  u16*   KKTe    = (u16*)(p + 17039360);           //    524,288 B
  u16*   vTb     = (u16*)(p + 17563648);           //  4,194,304 B
  u16*   WoT     = (u16*)(p + 21757952);           //  6,291,456 B
  u16*   q_bf    = (u16*)(p + 31457280);           // 12,582,912 B
  u16*   kv_bf   = (u16*)(p + 44040192);           //  8,388,608 B
  u16*   Pbar_bf = (u16*)(p + 44040192);           //  4,194,304 B (after kv dead)
  u16*   pv_out  = (u16*)(p + 48234496);           //  4,194,304 B
  float* bkv     = (float*)(p + 52428800);         //      8,192 B
  float* nrm4    = (float*)(p + 52436992);         //     16,384 B
  unsigned char* rowAny4 = (unsigned char*)(p + 52453376); // 4,096 B
  int*   anyCnt  = (int*)(p + 52457472);           //         16 B
  if (ws_size < 58916864) return;

  const dim3 tb(32, 8);
  const long long SS = (long long)SEQ * SEQ;       // 1,048,576
  const long long KVB = 2048LL * 1024;             // kv batch stride (elems) = 2,097,152

  // hs -> bf16 ; Wq^T ; q = hs @ Wq^T + bq  (grid 16x48 = 768 blocks, 3/CU)
  k_cvt_bf16<<<6144, 256, 0, stream>>>(hs, hs_bf, BATCH * SEQ * DIM / 4);
  k_tr_f32_bf16<<<dim3(96, 96), tb, 0, stream>>>(Wq, WqT, DIM, DIM);
  k_gemm_bt<true, true><<<dim3(768, 1), 256, 0, stream>>>(hs_bf, WqT, q_bf, bq,
      2048, DIM, DIM, DIM, DIM, DIM, 0, 0, 0, 0, 0, 0);
  // WkvT = [Wk^T ; Wv^T] ; bkv ; kv = hs @ WkvT^T + bkv  (grid 16x32 = 512)
  k_tr_f32_bf16<<<dim3(32, 96), tb, 0, stream>>>(Wk, WkvT, DIM, KDIM);
  k_tr_f32_bf16<<<dim3(32, 96), tb, 0, stream>>>(Wv, WkvT + (size_t)1024 * DIM, DIM, KDIM);
  k_bkv<<<8, 256, 0, stream>>>(bk, bv, bkv);
  k_gemm_bt<true, true><<<dim3(512, 1), 256, 0, stream>>>(hs_bf, WkvT, kv_bf, bkv,
      2048, 2048, DIM, DIM, DIM, 2048, 0, 0, 0, 0, 0, 0);
  // gram for all 4 slices (k/v x batch): zb = b*2 + kv  (grid 128x4 = 512)
  k_gemm_bt<false, false><<<dim3(128, 4), 256, 0, stream>>>(kv_bf, kv_bf, gram4, nullptr,
      SEQ, SEQ, KDIM, 2048, 2048, SEQ,
      KVB, 1024, KVB, 1024, 2 * SS, SS);
  k_norms<<<4, 1024, 0, stream>>>(gram4, nrm4, anyCnt);
  k_rowany<<<dim3(SEQ, 4), 256, 0, stream>>>(gram4, nrm4, rowAny4, anyCnt);
  k_scan_replace<<<4, 1024, 0, stream>>>(gram4, nrm4, rowAny4, anyCnt, kv_bf);
  // KKT = K_new @ [Wqk;bqk;0]^T per batch  (grid 16x2)
  k_build_wqke<<<128, 256, 0, stream>>>(Wqk, bqk, WqkE);
  k_gemm_bt<true, false><<<dim3(16, 2), 256, 0, stream>>>(kv_bf, WqkE, KKTe, nullptr,
      SEQ, 128, KDIM, 2048, KDIM, 128, 0, KVB, 0, 0, 0, (long long)SEQ * 128);
  // V^T per batch ; Wo^T
  k_tr_bf16<<<dim3(32, 32, 2), tb, 0, stream>>>(kv_bf + 1024, vTb, 2048, SEQ, KVB, SS);
  k_tr_f32_bf16<<<dim3(96, 32), tb, 0, stream>>>(Wo, WoT, KDIM, DIM);
  // attention probabilities + head-mean partials (no atomics)
  k_attn3<<<512, 1024, 0, stream>>>(q_bf, KKTe, pbarP);
  k_reduce_pbar<<<1024, 256, 0, stream>>>(pbarP, Pbar_bf);
  // pv = Pbar @ V per batch  (grid 128x2 = 256)
  k_gemm_bt<true, false><<<dim3(128, 2), 256, 0, stream>>>(Pbar_bf, vTb, pv_out, nullptr,
      SEQ, KDIM, SEQ, SEQ, SEQ, KDIM, 0, SS, 0, SS, 0, SS);
  // out = pv @ Wo + bo  (grid 16x48 = 768)
  k_gemm_bt<false, true><<<dim3(768, 1), 256, 0, stream>>>(pv_out, WoT, (float*)d_out, bo,
      2048, DIM, KDIM, KDIM, KDIM, DIM, 0, 0, 0, 0, 0, 0);
}